// Round 1
// baseline (390.825 us; speedup 1.0000x reference)
//
#include <hip/hip_runtime.h>
#include <hip/hip_bf16.h>
#include <cstdint>
#include <cstddef>

#define D_MODEL 1024
#define NHEAD   16
#define HDIM    64
#define BB      2
#define TT      2048
#define MM      (BB*TT)   // 4096 rows

typedef __attribute__((ext_vector_type(8))) __bf16 bf16x8;
typedef __attribute__((ext_vector_type(4))) float  f32x4;
typedef __attribute__((ext_vector_type(8))) unsigned short u16x8;
typedef __attribute__((ext_vector_type(4))) unsigned short u16x4;

__device__ __forceinline__ unsigned short f2b(float f){
  __bf16 b = (__bf16)f;
  return __builtin_bit_cast(unsigned short, b);
}

__device__ __forceinline__ f32x4 mfma16(bf16x8 a, bf16x8 b, f32x4 c){
  return __builtin_amdgcn_mfma_f32_16x16x32_bf16(a, b, c, 0, 0, 0);
}

// XOR swizzle: bijective within each 8-row stripe; applied identically on
// LDS write and read; spreads strided row reads across 8 16B bank groups.
#define SWZ(byteoff, row) ((byteoff) ^ (((row)&7)<<4))

// ---------------------------------------------------------------- cvt f32->bf16
__global__ void cvt_bf16_kernel(const float* __restrict__ x, unsigned short* __restrict__ y){
  size_t i = (size_t)blockIdx.x*blockDim.x + threadIdx.x;
  const float4* p = (const float4*)(x + i*8);
  float4 a = p[0], b = p[1];
  u16x8 o;
  o[0]=f2b(a.x); o[1]=f2b(a.y); o[2]=f2b(a.z); o[3]=f2b(a.w);
  o[4]=f2b(b.x); o[5]=f2b(b.y); o[6]=f2b(b.z); o[7]=f2b(b.w);
  *(u16x8*)(y + i*8) = o;
}

// ---------------------------------------------------- W[K][N] f32 -> Wt[N][K] bf16
__global__ void transpose_w_kernel(const float* __restrict__ W, unsigned short* __restrict__ Wt){
  __shared__ float tile[32][33];
  int tx = threadIdx.x, ty = threadIdx.y;
  int x0 = blockIdx.x*32, y0 = blockIdx.y*32;
  #pragma unroll
  for (int i=0;i<4;i++)
    tile[ty + i*8][tx] = W[(size_t)(y0 + ty + i*8)*D_MODEL + x0 + tx];
  __syncthreads();
  #pragma unroll
  for (int i=0;i<4;i++)
    Wt[(size_t)(x0 + ty + i*8)*D_MODEL + y0 + tx] = f2b(tile[tx][ty + i*8]);
}

// ---------------------------------------------------------------- GEMM (B^T form)
// C[M][N] = A[M][K] * Bt[N][K]^T + bias.   mode 0: bf16 row-major out
// mode 1: V-transposed out Vt[b][h][d][t] bf16.   mode 2: f32 row-major out.
__launch_bounds__(256)
__global__ void gemm_bt_kernel(const unsigned short* __restrict__ A,
                               const unsigned short* __restrict__ Bt,
                               const float* __restrict__ bias,
                               void* __restrict__ Cout, const int mode)
{
  constexpr int K = D_MODEL, N = D_MODEL;
  __shared__ unsigned short As[128*32];
  __shared__ unsigned short Bs[128*32];
  const int t = threadIdx.x;
  const int lane = t & 63, w = t >> 6;
  const int m0 = blockIdx.y*128, n0 = blockIdx.x*128;
  const int wr = w >> 1, wc = w & 1;
  const int lr = lane & 15, lg = lane >> 4;
  f32x4 acc[4][4] = {};
  for (int k0 = 0; k0 < K; k0 += 32){
    uint4 va[2], vb[2];
    #pragma unroll
    for (int i=0;i<2;i++){
      int c = i*256 + t; int r = c>>2, o = c&3;
      va[i] = *(const uint4*)(A  + (size_t)(m0+r)*K + k0 + o*8);
      vb[i] = *(const uint4*)(Bt + (size_t)(n0+r)*K + k0 + o*8);
    }
    __syncthreads();
    #pragma unroll
    for (int i=0;i<2;i++){
      int c = i*256 + t; int r = c>>2, o = c&3;
      int byte = SWZ(r*64 + o*16, r);
      *(uint4*)((char*)As + byte) = va[i];
      *(uint4*)((char*)Bs + byte) = vb[i];
    }
    __syncthreads();
    bf16x8 af[4], bfv[4];
    #pragma unroll
    for (int mi=0;mi<4;mi++){
      int r = wr*64 + mi*16 + lr;
      af[mi] = *(const bf16x8*)((const char*)As + SWZ(r*64 + lg*16, r));
    }
    #pragma unroll
    for (int ni=0;ni<4;ni++){
      int r = wc*64 + ni*16 + lr;
      bfv[ni] = *(const bf16x8*)((const char*)Bs + SWZ(r*64 + lg*16, r));
    }
    #pragma unroll
    for (int mi=0;mi<4;mi++)
      #pragma unroll
      for (int ni=0;ni<4;ni++)
        acc[mi][ni] = mfma16(af[mi], bfv[ni], acc[mi][ni]);
  }
  // epilogue: C/D frag mapping col=lane&15, row=(lane>>4)*4+reg
  #pragma unroll
  for (int mi=0;mi<4;mi++){
    #pragma unroll
    for (int ni=0;ni<4;ni++){
      int n = n0 + wc*64 + ni*16 + lr;
      int mbase = m0 + wr*64 + mi*16 + lg*4;
      float bv = bias[n];
      if (mode == 2){
        float* Cf = (float*)Cout;
        #pragma unroll
        for (int r=0;r<4;r++) Cf[(size_t)(mbase+r)*N + n] = acc[mi][ni][r] + bv;
      } else if (mode == 0){
        unsigned short* Cb = (unsigned short*)Cout;
        #pragma unroll
        for (int r=0;r<4;r++) Cb[(size_t)(mbase+r)*N + n] = f2b(acc[mi][ni][r] + bv);
      } else {
        unsigned short* Vt = (unsigned short*)Cout;
        int h = n >> 6, d = n & 63;
        int b = mbase >> 11;          // / TT
        int tq = mbase & (TT-1);
        u16x4 vv;
        #pragma unroll
        for (int r=0;r<4;r++) vv[r] = f2b(acc[mi][ni][r] + bv);
        *(u16x4*)(Vt + ((size_t)((b*NHEAD + h)*HDIM + d))*TT + tq) = vv;
      }
    }
  }
}

// ------------------------------------------------------- Pass A: column stats
// For each key column k: m_k = max_{q>=k} S[q,k], colS = 1/sum_{q>=k} exp(S-m_k)
// S = (Q . K)/8.  Block: 128 columns (wave w owns 32), streams q in 32-row tiles.
__launch_bounds__(256)
__global__ void col_stats_kernel(const unsigned short* __restrict__ Qb,
                                 const unsigned short* __restrict__ Kb,
                                 float* __restrict__ colM, float* __restrict__ colS)
{
  __shared__ unsigned short Ks[128*64];   // 16KB
  __shared__ unsigned short Qs[32*64];    // 4KB
  const int t = threadIdx.x, lane = t&63, w = t>>6;
  const int bh = blockIdx.y, b = bh >> 4, h = bh & 15;
  const int k0 = blockIdx.x * 128;
  const int lr = lane&15, lg = lane>>4;
  // stage K tile (rows = key index, 64 head dims)
  #pragma unroll
  for (int i=0;i<4;i++){
    int c = i*256 + t; int r = c>>3, o = c&7;
    uint4 vv = *(const uint4*)(Kb + ((size_t)(b*TT + k0 + r))*D_MODEL + h*64 + o*8);
    *(uint4*)((char*)Ks + SWZ(r*128 + o*16, r)) = vv;
  }
  __syncthreads();
  bf16x8 bk[2][2];
  #pragma unroll
  for (int kb=0;kb<2;kb++)
    #pragma unroll
    for (int ks=0;ks<2;ks++){
      int r = w*32 + kb*16 + lr;
      bk[kb][ks] = *(const bf16x8*)((const char*)Ks + SWZ(r*128 + ks*64 + lg*16, r));
    }
  float mreg[2] = {-1e30f,-1e30f}, sreg[2] = {0.f,0.f};
  for (int qt = k0; qt < TT; qt += 32){
    __syncthreads();   // Qs reuse guard
    { int r = t>>3, o = t&7;
      uint4 vv = *(const uint4*)(Qb + ((size_t)(b*TT + qt + r))*D_MODEL + h*64 + o*8);
      *(uint4*)((char*)Qs + SWZ(r*128 + o*16, r)) = vv; }
    __syncthreads();
    f32x4 sf[2][2] = {};  // [qb][kb]
    #pragma unroll
    for (int ks=0;ks<2;ks++){
      bf16x8 aq[2];
      #pragma unroll
      for (int qb=0;qb<2;qb++){
        int r = qb*16 + lr;
        aq[qb] = *(const bf16x8*)((const char*)Qs + SWZ(r*128 + ks*64 + lg*16, r));
      }
      #pragma unroll
      for (int qb=0;qb<2;qb++)
        #pragma unroll
        for (int kb=0;kb<2;kb++)
          sf[qb][kb] = mfma16(aq[qb], bk[kb][ks], sf[qb][kb]);
    }
    #pragma unroll
    for (int kb=0;kb<2;kb++){
      int col = k0 + w*32 + kb*16 + lr;
      float tm = -1e30f;
      float sv[2][4];
      #pragma unroll
      for (int qb=0;qb<2;qb++)
        #pragma unroll
        for (int r=0;r<4;r++){
          int qg = qt + qb*16 + lg*4 + r;
          float s = sf[qb][kb][r] * 0.125f;
          s = (qg >= col) ? s : -1e30f;   // masked; self-flushing online update
          sv[qb][r] = s;
          tm = fmaxf(tm, s);
        }
      tm = fmaxf(tm, __shfl_xor(tm, 16));
      tm = fmaxf(tm, __shfl_xor(tm, 32));
      float mnew = fmaxf(mreg[kb], tm);
      float part = 0.f;
      #pragma unroll
      for (int qb=0;qb<2;qb++)
        #pragma unroll
        for (int r=0;r<4;r++)
          part += __expf(sv[qb][r] - mnew);
      part += __shfl_xor(part, 16);
      part += __shfl_xor(part, 32);
      sreg[kb] = sreg[kb]*__expf(mreg[kb]-mnew) + part;
      mreg[kb] = mnew;
    }
  }
  if (lg == 0){
    #pragma unroll
    for (int kb=0;kb<2;kb++){
      int col = k0 + w*32 + kb*16 + lr;
      colM[(size_t)bh*TT + col] = mreg[kb];
      colS[(size_t)bh*TT + col] = 1.0f / sreg[kb];   // store inverse
    }
  }
}

// ------------------------------------------------------------- Pass B: output
// O[q,:] = sum_{k<=q} exp(S[q,k]-m_k)*invs_k * V[k,:]   (bf16 out, [M][D] layout)
__launch_bounds__(256)
__global__ void attn_out_kernel(const unsigned short* __restrict__ Qb,
                                const unsigned short* __restrict__ Kb,
                                const unsigned short* __restrict__ Vt,
                                const float* __restrict__ colM,
                                const float* __restrict__ colS,
                                unsigned short* __restrict__ O)
{
  __shared__ unsigned short Qs[128*64];   // 16KB
  __shared__ unsigned short Ks2[64*64];   //  8KB
  __shared__ unsigned short Vs[64*64];    //  8KB
  __shared__ float Ps[128*64];            // 32KB (f32, swizzled; per-wave private rows)
  const int t = threadIdx.x, lane=t&63, w=t>>6;
  const int bh = blockIdx.y, b = bh>>4, h = bh&15;
  const int q0 = ((int)gridDim.x - 1 - (int)blockIdx.x) * 128;  // heavy blocks first
  const int lr = lane&15, lg = lane>>4;
  #pragma unroll
  for (int i=0;i<4;i++){
    int c = i*256+t; int r=c>>3, o=c&7;
    uint4 vv = *(const uint4*)(Qb + ((size_t)(b*TT + q0 + r))*D_MODEL + h*64 + o*8);
    *(uint4*)((char*)Qs + SWZ(r*128 + o*16, r)) = vv;
  }
  __syncthreads();
  bf16x8 aq[2][2];
  #pragma unroll
  for (int qb=0;qb<2;qb++)
    #pragma unroll
    for (int ks=0;ks<2;ks++){
      int r = w*32 + qb*16 + lr;
      aq[qb][ks] = *(const bf16x8*)((const char*)Qs + SWZ(r*128 + ks*64 + lg*16, r));
    }
  f32x4 oacc[2][4] = {};   // [qb][db]
  const int nkt = q0/64 + 2;
  for (int kt=0; kt<nkt; kt++){
    int k0 = kt*64;
    __syncthreads();  // K/V/P reuse guard
    #pragma unroll
    for (int i=0;i<2;i++){
      int c = i*256+t; int r=c>>3, o=c&7;
      uint4 vk = *(const uint4*)(Kb + ((size_t)(b*TT + k0 + r))*D_MODEL + h*64 + o*8);
      uint4 vv = *(const uint4*)(Vt + ((size_t)(bh*HDIM + r))*TT + k0 + o*8);
      int byte = SWZ(r*128 + o*16, r);
      *(uint4*)((char*)Ks2 + byte) = vk;
      *(uint4*)((char*)Vs  + byte) = vv;
    }
    __syncthreads();
    // S = Q K^T (bit-identical MFMA sequence to pass A)
    f32x4 sf[2][4] = {};
    #pragma unroll
    for (int ks=0;ks<2;ks++){
      bf16x8 bk[4];
      #pragma unroll
      for (int kb=0;kb<4;kb++){
        int r = kb*16 + lr;
        bk[kb] = *(const bf16x8*)((const char*)Ks2 + SWZ(r*128 + ks*64 + lg*16, r));
      }
      #pragma unroll
      for (int qb=0;qb<2;qb++)
        #pragma unroll
        for (int kb=0;kb<4;kb++)
          sf[qb][kb] = mfma16(aq[qb][ks], bk[kb], sf[qb][kb]);
    }
    // P = exp(S/8 - m_col) * invs_col (0 where masked); write to swizzled f32 LDS
    #pragma unroll
    for (int kb=0;kb<4;kb++){
      int col = k0 + kb*16 + lr;
      float mc  = colM[(size_t)bh*TT + col];
      float isc = colS[(size_t)bh*TT + col];
      #pragma unroll
      for (int qb=0;qb<2;qb++){
        #pragma unroll
        for (int r=0;r<4;r++){
          int prow = w*32 + qb*16 + lg*4 + r;
          int qg = q0 + prow;
          float s = sf[qb][kb][r]*0.125f;
          float pv = (qg >= col) ? __expf(s - mc)*isc : 0.f;
          *(float*)((char*)Ps + SWZ((prow*64 + kb*16 + lr)*4, prow)) = pv;
        }
      }
    }
    // (Ps rows are wave-private; in-wave LDS ordering suffices, no barrier)
    #pragma unroll
    for (int ks=0;ks<2;ks++){
      bf16x8 pa[2];
      #pragma unroll
      for (int qb=0;qb<2;qb++){
        int prow = w*32 + qb*16 + lr;
        int byte0 = SWZ((prow*64 + ks*32 + lg*8)*4, prow);
        f32x4 p0 = *(const f32x4*)((const char*)Ps + byte0);
        f32x4 p1 = *(const f32x4*)((const char*)Ps + (byte0 ^ 16));
        bf16x8 pv;
        #pragma unroll
        for (int j=0;j<4;j++){ pv[j] = (__bf16)p0[j]; pv[j+4] = (__bf16)p1[j]; }
        pa[qb] = pv;
      }
      bf16x8 bv[4];
      #pragma unroll
      for (int db=0;db<4;db++){
        int r = db*16 + lr;
        bv[db] = *(const bf16x8*)((const char*)Vs + SWZ(r*128 + ks*64 + lg*16, r));
      }
      #pragma unroll
      for (int qb=0;qb<2;qb++)
        #pragma unroll
        for (int db=0;db<4;db++)
          oacc[qb][db] = mfma16(pa[qb], bv[db], oacc[qb][db]);
    }
  }
  // epilogue: O in [B*T][D_MODEL] bf16 at this head's column slice
  #pragma unroll
  for (int qb=0;qb<2;qb++)
    #pragma unroll
    for (int db=0;db<4;db++){
      int qg = q0 + w*32 + qb*16 + lg*4;
      int d  = db*16 + lr;
      #pragma unroll
      for (int r=0;r<4;r++)
        O[((size_t)(b*TT + qg + r))*D_MODEL + h*64 + d] = f2b(oacc[qb][db][r]);
    }
}

// ---------------------------------------------------------------------- launch
extern "C" void kernel_launch(void* const* d_in, const int* in_sizes, int n_in,
                              void* d_out, int out_size, void* d_ws, size_t ws_size,
                              hipStream_t stream)
{
  (void)in_sizes; (void)n_in; (void)out_size; (void)ws_size;
  const float* q   = (const float*)d_in[0];
  const float* k   = (const float*)d_in[1];
  const float* v   = (const float*)d_in[2];
  const float* w_q = (const float*)d_in[3];
  const float* b_q = (const float*)d_in[4];
  const float* w_k = (const float*)d_in[5];
  const float* b_k = (const float*)d_in[6];
  const float* w_v = (const float*)d_in[7];
  const float* b_v = (const float*)d_in[8];
  const float* w_o = (const float*)d_in[9];
  const float* b_o = (const float*)d_in[10];

  char* p = (char*)d_ws;
  auto carve = [&](size_t bytes)->char* {
    char* r = p; p += (bytes + 255) & ~(size_t)255; return r;
  };
  unsigned short* Xq  = (unsigned short*)carve((size_t)MM*D_MODEL*2);
  unsigned short* Xk  = (unsigned short*)carve((size_t)MM*D_MODEL*2);
  unsigned short* Xv  = (unsigned short*)carve((size_t)MM*D_MODEL*2);
  unsigned short* Wtq = (unsigned short*)carve((size_t)D_MODEL*D_MODEL*2);
  unsigned short* Wtk = (unsigned short*)carve((size_t)D_MODEL*D_MODEL*2);
  unsigned short* Wtv = (unsigned short*)carve((size_t)D_MODEL*D_MODEL*2);
  unsigned short* Wto = (unsigned short*)carve((size_t)D_MODEL*D_MODEL*2);
  unsigned short* Qb  = (unsigned short*)carve((size_t)MM*D_MODEL*2);
  unsigned short* Kb  = (unsigned short*)carve((size_t)MM*D_MODEL*2);
  unsigned short* Vt  = (unsigned short*)carve((size_t)MM*D_MODEL*2);
  unsigned short* Ob  = (unsigned short*)carve((size_t)MM*D_MODEL*2);
  float* colM = (float*)carve((size_t)BB*NHEAD*TT*4);
  float* colS = (float*)carve((size_t)BB*NHEAD*TT*4);

  const int nblk_cvt = (MM*D_MODEL/8)/256;   // 2048
  cvt_bf16_kernel<<<nblk_cvt, 256, 0, stream>>>(q, Xq);
  cvt_bf16_kernel<<<nblk_cvt, 256, 0, stream>>>(k, Xk);
  cvt_bf16_kernel<<<nblk_cvt, 256, 0, stream>>>(v, Xv);

  dim3 tgrid(32,32), tblk(32,8);
  transpose_w_kernel<<<tgrid, tblk, 0, stream>>>(w_q, Wtq);
  transpose_w_kernel<<<tgrid, tblk, 0, stream>>>(w_k, Wtk);
  transpose_w_kernel<<<tgrid, tblk, 0, stream>>>(w_v, Wtv);
  transpose_w_kernel<<<tgrid, tblk, 0, stream>>>(w_o, Wto);

  dim3 ggrid(D_MODEL/128, MM/128);  // (8, 32)
  gemm_bt_kernel<<<ggrid, 256, 0, stream>>>(Xq, Wtq, b_q, Qb, 0);
  gemm_bt_kernel<<<ggrid, 256, 0, stream>>>(Xk, Wtk, b_k, Kb, 0);
  gemm_bt_kernel<<<ggrid, 256, 0, stream>>>(Xv, Wtv, b_v, Vt, 1);

  dim3 agrid(TT/128, BB*NHEAD);     // (16, 32)
  col_stats_kernel<<<agrid, 256, 0, stream>>>(Qb, Kb, colM, colS);
  attn_out_kernel<<<agrid, 256, 0, stream>>>(Qb, Kb, Vt, colM, colS, Ob);

  gemm_bt_kernel<<<ggrid, 256, 0, stream>>>(Ob, Wto, b_o, d_out, 2);
}

// Round 2
// 228.744 us; speedup vs baseline: 1.7086x; 1.7086x over previous
//
#include <hip/hip_runtime.h>
#include <hip/hip_bf16.h>
#include <cstdint>
#include <cstddef>

#define D_MODEL 1024
#define NHEAD   16
#define HDIM    64
#define BB      2
#define TT      2048
#define MM      (BB*TT)   // 4096 rows
#define BHN     (BB*NHEAD) // 32

typedef __attribute__((ext_vector_type(8))) __bf16 bf16x8;
typedef __attribute__((ext_vector_type(4))) float  f32x4;
typedef __attribute__((ext_vector_type(8))) unsigned short u16x8;
typedef __attribute__((ext_vector_type(4))) unsigned short u16x4;

__device__ __forceinline__ unsigned short f2b(float f){
  __bf16 b = (__bf16)f;
  return __builtin_bit_cast(unsigned short, b);
}

__device__ __forceinline__ f32x4 mfma16(bf16x8 a, bf16x8 b, f32x4 c){
  return __builtin_amdgcn_mfma_f32_16x16x32_bf16(a, b, c, 0, 0, 0);
}

// XOR swizzle: bijective within each 8-row stripe; applied identically on
// LDS write and read; spreads strided row reads across 8 16B bank groups.
#define SWZ(byteoff, row) ((byteoff) ^ (((row)&7)<<4))

// ------------------------------------------- W[K][N] f32 -> Wt[N][K] bf16 (x4 fused)
__global__ void transpose_w_kernel(const float* __restrict__ W0, const float* __restrict__ W1,
                                   const float* __restrict__ W2, const float* __restrict__ W3,
                                   unsigned short* __restrict__ T0, unsigned short* __restrict__ T1,
                                   unsigned short* __restrict__ T2, unsigned short* __restrict__ T3){
  __shared__ float tile[32][33];
  const int z = blockIdx.z;
  const float* W = z==0 ? W0 : z==1 ? W1 : z==2 ? W2 : W3;
  unsigned short* Wt = z==0 ? T0 : z==1 ? T1 : z==2 ? T2 : T3;
  int tx = threadIdx.x, ty = threadIdx.y;
  int x0 = blockIdx.x*32, y0 = blockIdx.y*32;
  #pragma unroll
  for (int i=0;i<4;i++)
    tile[ty + i*8][tx] = W[(size_t)(y0 + ty + i*8)*D_MODEL + x0 + tx];
  __syncthreads();
  #pragma unroll
  for (int i=0;i<4;i++)
    Wt[(size_t)(x0 + ty + i*8)*D_MODEL + y0 + tx] = f2b(tile[tx][ty + i*8]);
}

// ---------------------------------------------------------------- GEMM (B^T form)
// C[M][N] = A[M][K] * Bt[N][K]^T + bias.  AF32: A is f32, converted during staging.
// mode 0: bf16 row-major out.  mode 1: V-transposed out Vt[b][h][d][t] bf16.
// mode 2: f32 row-major out.
template<bool AF32>
__device__ __forceinline__ void gemm_body(const void* __restrict__ A_,
                                          const unsigned short* __restrict__ Bt,
                                          const float* __restrict__ bias,
                                          void* __restrict__ Cout, const int mode)
{
  constexpr int K = D_MODEL, N = D_MODEL;
  __shared__ unsigned short As[128*32];
  __shared__ unsigned short Bs[128*32];
  const int t = threadIdx.x;
  const int lane = t & 63, w = t >> 6;
  const int m0 = blockIdx.y*128, n0 = blockIdx.x*128;
  const int wr = w >> 1, wc = w & 1;
  const int lr = lane & 15, lg = lane >> 4;
  f32x4 acc[4][4] = {};
  for (int k0 = 0; k0 < K; k0 += 32){
    uint4 va[2], vb[2];
    #pragma unroll
    for (int i=0;i<2;i++){
      int c = i*256 + t; int r = c>>2, o = c&3;
      if constexpr (AF32){
        const float* A = (const float*)A_;
        const float4* p = (const float4*)(A + (size_t)(m0+r)*K + k0 + o*8);
        float4 f0 = p[0], f1 = p[1];
        u16x8 pk;
        pk[0]=f2b(f0.x); pk[1]=f2b(f0.y); pk[2]=f2b(f0.z); pk[3]=f2b(f0.w);
        pk[4]=f2b(f1.x); pk[5]=f2b(f1.y); pk[6]=f2b(f1.z); pk[7]=f2b(f1.w);
        va[i] = __builtin_bit_cast(uint4, pk);
      } else {
        const unsigned short* A = (const unsigned short*)A_;
        va[i] = *(const uint4*)(A + (size_t)(m0+r)*K + k0 + o*8);
      }
      vb[i] = *(const uint4*)(Bt + (size_t)(n0+r)*K + k0 + o*8);
    }
    __syncthreads();
    #pragma unroll
    for (int i=0;i<2;i++){
      int c = i*256 + t; int r = c>>2, o = c&3;
      int byte = SWZ(r*64 + o*16, r);
      *(uint4*)((char*)As + byte) = va[i];
      *(uint4*)((char*)Bs + byte) = vb[i];
    }
    __syncthreads();
    bf16x8 af[4], bfv[4];
    #pragma unroll
    for (int mi=0;mi<4;mi++){
      int r = wr*64 + mi*16 + lr;
      af[mi] = *(const bf16x8*)((const char*)As + SWZ(r*64 + lg*16, r));
    }
    #pragma unroll
    for (int ni=0;ni<4;ni++){
      int r = wc*64 + ni*16 + lr;
      bfv[ni] = *(const bf16x8*)((const char*)Bs + SWZ(r*64 + lg*16, r));
    }
    #pragma unroll
    for (int mi=0;mi<4;mi++)
      #pragma unroll
      for (int ni=0;ni<4;ni++)
        acc[mi][ni] = mfma16(af[mi], bfv[ni], acc[mi][ni]);
  }
  // epilogue: C/D frag mapping col=lane&15, row=(lane>>4)*4+reg
  #pragma unroll
  for (int mi=0;mi<4;mi++){
    #pragma unroll
    for (int ni=0;ni<4;ni++){
      int n = n0 + wc*64 + ni*16 + lr;
      int mbase = m0 + wr*64 + mi*16 + lg*4;
      float bv = bias[n];
      if (mode == 2){
        float* Cf = (float*)Cout;
        #pragma unroll
        for (int r=0;r<4;r++) Cf[(size_t)(mbase+r)*N + n] = acc[mi][ni][r] + bv;
      } else if (mode == 0){
        unsigned short* Cb = (unsigned short*)Cout;
        #pragma unroll
        for (int r=0;r<4;r++) Cb[(size_t)(mbase+r)*N + n] = f2b(acc[mi][ni][r] + bv);
      } else {
        unsigned short* Vt = (unsigned short*)Cout;
        int h = n >> 6, d = n & 63;
        int b = mbase >> 11;          // / TT
        int tq = mbase & (TT-1);
        u16x4 vv;
        #pragma unroll
        for (int r=0;r<4;r++) vv[r] = f2b(acc[mi][ni][r] + bv);
        *(u16x4*)(Vt + ((size_t)((b*NHEAD + h)*HDIM + d))*TT + tq) = vv;
      }
    }
  }
}

__launch_bounds__(256)
__global__ void proj_gemm_kernel(const float* __restrict__ q, const float* __restrict__ k,
                                 const float* __restrict__ v,
                                 const unsigned short* __restrict__ Wtq,
                                 const unsigned short* __restrict__ Wtk,
                                 const unsigned short* __restrict__ Wtv,
                                 const float* __restrict__ b_q, const float* __restrict__ b_k,
                                 const float* __restrict__ b_v,
                                 unsigned short* __restrict__ Qb, unsigned short* __restrict__ Kb,
                                 unsigned short* __restrict__ Vt)
{
  const int z = blockIdx.z;
  const void* A = z==0 ? (const void*)q : z==1 ? (const void*)k : (const void*)v;
  const unsigned short* Bt = z==0 ? Wtq : z==1 ? Wtk : Wtv;
  const float* bias = z==0 ? b_q : z==1 ? b_k : b_v;
  void* C = z==0 ? (void*)Qb : z==1 ? (void*)Kb : (void*)Vt;
  gemm_body<true>(A, Bt, bias, C, z==2 ? 1 : 0);
}

__launch_bounds__(256)
__global__ void out_gemm_kernel(const unsigned short* __restrict__ Ob,
                                const unsigned short* __restrict__ Wto,
                                const float* __restrict__ b_o, float* __restrict__ out)
{
  gemm_body<false>(Ob, Wto, b_o, out, 2);
}

// ------------------------------------------------------- Pass A: column sums
// No max subtraction (|S| <~ 8, exp sums fit f32 comfortably).
// partialS[qc][bh][col] = sum_{q in chunk qc, q>=col} exp(S[q,col])
// Block: 128 cols x one 256-row q-chunk.  Deterministic (no atomics).
__launch_bounds__(256)
__global__ void col_stats_kernel(const unsigned short* __restrict__ Qb,
                                 const unsigned short* __restrict__ Kb,
                                 float* __restrict__ partialS)
{
  __shared__ unsigned short Ks[128*64];   // 16KB
  __shared__ unsigned short Qs[64*64];    // 8KB
  const int t = threadIdx.x, lane = t&63, w = t>>6;
  const int id = blockIdx.x;
  const int bh = id & 31, pair = id >> 5;   // XCD = id%8 = bh%8 -> per-bh L2 locality
  const int kb_ = pair & 15, qc = pair >> 4;
  const int b = bh >> 4, h = bh & 15;
  const int k0 = kb_ * 128;
  const int lr = lane&15, lg = lane>>4;
  // stage K tile (128 keys x 64 dims)
  #pragma unroll
  for (int i=0;i<4;i++){
    int c = i*256 + t; int r = c>>3, o = c&7;
    uint4 vv = *(const uint4*)(Kb + ((size_t)(b*TT + k0 + r))*D_MODEL + h*64 + o*8);
    *(uint4*)((char*)Ks + SWZ(r*128 + o*16, r)) = vv;
  }
  __syncthreads();
  bf16x8 bk[2][2];
  #pragma unroll
  for (int kb=0;kb<2;kb++)
    #pragma unroll
    for (int ks=0;ks<2;ks++){
      int r = w*32 + kb*16 + lr;
      bk[kb][ks] = *(const bf16x8*)((const char*)Ks + SWZ(r*128 + ks*64 + lg*16, r));
    }
  f32x4 sacc[2] = {};   // 4 independent accumulation chains per column group
  const int qstart = (k0 > qc*256) ? k0 : qc*256;
  const int qend   = (qc+1)*256;
  for (int qt = qstart; qt < qend; qt += 64){
    __syncthreads();   // Qs reuse guard
    #pragma unroll
    for (int i=0;i<2;i++){
      int c = i*256 + t; int r = c>>3, o = c&7;
      uint4 vv = *(const uint4*)(Qb + ((size_t)(b*TT + qt + r))*D_MODEL + h*64 + o*8);
      *(uint4*)((char*)Qs + SWZ(r*128 + o*16, r)) = vv;
    }
    __syncthreads();
    const bool interior = (qt >= k0 + 128);   // no masking needed
    #pragma unroll
    for (int qb=0;qb<4;qb++){
      bf16x8 aq[2];
      #pragma unroll
      for (int ks=0;ks<2;ks++){
        int r = qb*16 + lr;
        aq[ks] = *(const bf16x8*)((const char*)Qs + SWZ(r*128 + ks*64 + lg*16, r));
      }
      f32x4 sf[2] = {};
      #pragma unroll
      for (int ks=0;ks<2;ks++)
        #pragma unroll
        for (int kb=0;kb<2;kb++)
          sf[kb] = mfma16(aq[ks], bk[kb][ks], sf[kb]);
      #pragma unroll
      for (int kb=0;kb<2;kb++){
        int col = k0 + w*32 + kb*16 + lr;
        #pragma unroll
        for (int r=0;r<4;r++){
          float e = __expf(sf[kb][r] * 0.125f);
          if (!interior){
            int qg = qt + qb*16 + lg*4 + r;
            e = (qg >= col) ? e : 0.f;
          }
          sacc[kb][r] += e;
        }
      }
    }
  }
  #pragma unroll
  for (int kb=0;kb<2;kb++){
    float s = sacc[kb][0] + sacc[kb][1] + sacc[kb][2] + sacc[kb][3];
    s += __shfl_xor(s, 16);
    s += __shfl_xor(s, 32);
    if (lg == 0){
      int col = k0 + w*32 + kb*16 + lr;
      partialS[((size_t)qc*BHN + bh)*TT + col] = s;
    }
  }
}

// combine 8 partials -> colS = 1/sum
__global__ void col_combine_kernel(const float* __restrict__ partialS, float* __restrict__ colS){
  int i = blockIdx.x*256 + threadIdx.x;   // [0, 32*2048)
  float s = 0.f;
  #pragma unroll
  for (int qc=0;qc<8;qc++) s += partialS[(size_t)qc*BHN*TT + i];
  colS[i] = 1.0f / s;
}

// ------------------------------------------------------------- Pass B: output
// O[q,:] = sum_{k<=q} exp(S[q,k])*invs_k * V[k,:]   (bf16 out, [M][D] layout)
// 64-q-row blocks, wave owns 16 rows; P staged as bf16 in LDS (wave-private rows).
__launch_bounds__(256)
__global__ void attn_out_kernel(const unsigned short* __restrict__ Qb,
                                const unsigned short* __restrict__ Kb,
                                const unsigned short* __restrict__ Vt,
                                const float* __restrict__ colS,
                                unsigned short* __restrict__ O)
{
  __shared__ unsigned short Qs[64*64];    // 8KB
  __shared__ unsigned short Ks2[64*64];   // 8KB
  __shared__ unsigned short Vs[64*64];    // 8KB
  __shared__ unsigned short Ps[64*64];    // 8KB bf16
  const int t = threadIdx.x, lane=t&63, w=t>>6;
  const int id = blockIdx.x;
  const int bh = id & 31;                 // XCD = bh%8 -> K/V stay in one XCD's L2
  const int qi = 31 - (id >> 5);          // heavy blocks dispatched first
  const int b = bh>>4, h = bh&15;
  const int q0 = qi*64;
  const int lr = lane&15, lg = lane>>4;
  #pragma unroll
  for (int i=0;i<2;i++){
    int c = i*256+t; int r=c>>3, o=c&7;
    uint4 vv = *(const uint4*)(Qb + ((size_t)(b*TT + q0 + r))*D_MODEL + h*64 + o*8);
    *(uint4*)((char*)Qs + SWZ(r*128 + o*16, r)) = vv;
  }
  __syncthreads();
  bf16x8 aq[2];
  #pragma unroll
  for (int ks=0;ks<2;ks++){
    int r = w*16 + lr;
    aq[ks] = *(const bf16x8*)((const char*)Qs + SWZ(r*128 + ks*64 + lg*16, r));
  }
  f32x4 oacc[4] = {};
  const int nkt = qi + 1;
  for (int kt=0; kt<nkt; kt++){
    int k0 = kt*64;
    __syncthreads();  // K/V reuse guard
    #pragma unroll
    for (int i=0;i<2;i++){
      int c = i*256+t; int r=c>>3, o=c&7;
      uint4 vk = *(const uint4*)(Kb + ((size_t)(b*TT + k0 + r))*D_MODEL + h*64 + o*8);
      uint4 vv = *(const uint4*)(Vt + ((size_t)(bh*HDIM + r))*TT + k0 + o*8);
      int byte = SWZ(r*128 + o*16, r);
      *(uint4*)((char*)Ks2 + byte) = vk;
      *(uint4*)((char*)Vs  + byte) = vv;
    }
    __syncthreads();
    // S = Q K^T
    f32x4 sf[4] = {};
    #pragma unroll
    for (int ks=0;ks<2;ks++)
      #pragma unroll
      for (int kb=0;kb<4;kb++){
        int r = kb*16 + lr;
        bf16x8 bk = *(const bf16x8*)((const char*)Ks2 + SWZ(r*128 + ks*64 + lg*16, r));
        sf[kb] = mfma16(aq[ks], bk, sf[kb]);
      }
    // P = exp(S)*invs (0 where masked), bf16 into swizzled LDS (wave-private rows)
    const bool boundary = (kt == qi);
    #pragma unroll
    for (int kb=0;kb<4;kb++){
      int col = k0 + kb*16 + lr;
      float isc = colS[(size_t)bh*TT + col];
      #pragma unroll
      for (int r=0;r<4;r++){
        int prow = w*16 + lg*4 + r;
        float pv = __expf(sf[kb][r]*0.125f) * isc;
        if (boundary){
          int qg = q0 + prow;
          pv = (qg >= col) ? pv : 0.f;
        }
        *(unsigned short*)((char*)Ps + SWZ((prow*64 + kb*16 + lr)*2, prow)) = f2b(pv);
      }
    }
    // (Ps rows wave-private; in-wave lgkmcnt ordering suffices, no barrier)
    #pragma unroll
    for (int ks=0;ks<2;ks++){
      int pr = w*16 + lr;
      bf16x8 pa = *(const bf16x8*)((const char*)Ps + SWZ(pr*128 + ks*64 + lg*16, pr));
      #pragma unroll
      for (int db=0;db<4;db++){
        int r = db*16 + lr;
        bf16x8 bv = *(const bf16x8*)((const char*)Vs + SWZ(r*128 + ks*64 + lg*16, r));
        oacc[db] = mfma16(pa, bv, oacc[db]);
      }
    }
  }
  #pragma unroll
  for (int db=0;db<4;db++){
    int qg = q0 + w*16 + lg*4;
    int d  = db*16 + lr;
    #pragma unroll
    for (int r=0;r<4;r++)
      O[((size_t)(b*TT + qg + r))*D_MODEL + h*64 + d] = f2b(oacc[db][r]);
  }
}

// ---------------------------------------------------------------------- launch
extern "C" void kernel_launch(void* const* d_in, const int* in_sizes, int n_in,
                              void* d_out, int out_size, void* d_ws, size_t ws_size,
                              hipStream_t stream)
{
  (void)in_sizes; (void)n_in; (void)out_size; (void)ws_size;
  const float* q   = (const float*)d_in[0];
  const float* k   = (const float*)d_in[1];
  const float* v   = (const float*)d_in[2];
  const float* w_q = (const float*)d_in[3];
  const float* b_q = (const float*)d_in[4];
  const float* w_k = (const float*)d_in[5];
  const float* b_k = (const float*)d_in[6];
  const float* w_v = (const float*)d_in[7];
  const float* b_v = (const float*)d_in[8];
  const float* w_o = (const float*)d_in[9];
  const float* b_o = (const float*)d_in[10];

  char* p = (char*)d_ws;
  auto carve = [&](size_t bytes)->char* {
    char* r = p; p += (bytes + 255) & ~(size_t)255; return r;
  };
  unsigned short* Wtq = (unsigned short*)carve((size_t)D_MODEL*D_MODEL*2);
  unsigned short* Wtk = (unsigned short*)carve((size_t)D_MODEL*D_MODEL*2);
  unsigned short* Wtv = (unsigned short*)carve((size_t)D_MODEL*D_MODEL*2);
  unsigned short* Wto = (unsigned short*)carve((size_t)D_MODEL*D_MODEL*2);
  unsigned short* Qb  = (unsigned short*)carve((size_t)MM*D_MODEL*2);
  unsigned short* Kb  = (unsigned short*)carve((size_t)MM*D_MODEL*2);
  unsigned short* Vt  = (unsigned short*)carve((size_t)MM*D_MODEL*2);
  unsigned short* Ob  = (unsigned short*)carve((size_t)MM*D_MODEL*2);
  float* partialS = (float*)carve((size_t)8*BHN*TT*4);
  float* colS     = (float*)carve((size_t)BHN*TT*4);

  dim3 tgrid(32,32,4), tblk(32,8);
  transpose_w_kernel<<<tgrid, tblk, 0, stream>>>(w_q, w_k, w_v, w_o, Wtq, Wtk, Wtv, Wto);

  dim3 pgrid(D_MODEL/128, MM/128, 3);   // (8, 32, 3)
  proj_gemm_kernel<<<pgrid, 256, 0, stream>>>(q, k, v, Wtq, Wtk, Wtv, b_q, b_k, b_v, Qb, Kb, Vt);

  col_stats_kernel<<<dim3(8*16*BHN), 256, 0, stream>>>(Qb, Kb, partialS);   // 4096 blocks
  col_combine_kernel<<<dim3(BHN*TT/256), 256, 0, stream>>>(partialS, colS); // 256 blocks

  attn_out_kernel<<<dim3((TT/64)*BHN), 256, 0, stream>>>(Qb, Kb, Vt, colS, Ob); // 1024 blocks

  dim3 ggrid(D_MODEL/128, MM/128);      // (8, 32)
  out_gemm_kernel<<<ggrid, 256, 0, stream>>>(Ob, Wto, b_o, (float*)d_out);
}

// Round 3
// 167.159 us; speedup vs baseline: 2.3380x; 1.3684x over previous
//
#include <hip/hip_runtime.h>
#include <hip/hip_bf16.h>
#include <cstdint>
#include <cstddef>

#define D_MODEL 1024
#define NHEAD   16
#define HDIM    64
#define BB      2
#define TT      2048
#define MM      (BB*TT)    // 4096 rows
#define BHN     (BB*NHEAD) // 32

typedef __attribute__((ext_vector_type(8))) __bf16 bf16x8;
typedef __attribute__((ext_vector_type(4))) float  f32x4;
typedef __attribute__((ext_vector_type(8))) unsigned short u16x8;
typedef __attribute__((ext_vector_type(4))) unsigned short u16x4;

__device__ __forceinline__ unsigned short f2b(float f){
  __bf16 b = (__bf16)f;
  return __builtin_bit_cast(unsigned short, b);
}

__device__ __forceinline__ f32x4 mfma16(bf16x8 a, bf16x8 b, f32x4 c){
  return __builtin_amdgcn_mfma_f32_16x16x32_bf16(a, b, c, 0, 0, 0);
}

// async global->LDS, 16B per lane; LDS dest = base + lane*16 (linear).
__device__ __forceinline__ void gload16(const void* g, void* lds){
  __builtin_amdgcn_global_load_lds((const __attribute__((address_space(1))) void*)g,
                                   (__attribute__((address_space(3))) void*)lds, 16, 0, 0);
}

// XOR swizzle for 128B-row LDS tiles: flips byte bits 4-6, all within-row
// (row boundary at bit 7) -> bijective per row, spreads 8 rows over 8 slots.
#define SWZ(byteoff, row) ((byteoff) ^ (((row)&7)<<4))

// ------------------------------------------------- cvt f32 -> bf16 (q,k,v fused)
__global__ void cvt_bf16_kernel(const float* __restrict__ q, const float* __restrict__ k,
                                const float* __restrict__ v,
                                unsigned short* __restrict__ Xq, unsigned short* __restrict__ Xk,
                                unsigned short* __restrict__ Xv){
  const int z = blockIdx.y;
  const float* x = z==0 ? q : z==1 ? k : v;
  unsigned short* y = z==0 ? Xq : z==1 ? Xk : Xv;
  size_t i = (size_t)blockIdx.x*blockDim.x + threadIdx.x;
  const float4* p = (const float4*)(x + i*8);
  float4 a = p[0], b = p[1];
  u16x8 o;
  o[0]=f2b(a.x); o[1]=f2b(a.y); o[2]=f2b(a.z); o[3]=f2b(a.w);
  o[4]=f2b(b.x); o[5]=f2b(b.y); o[6]=f2b(b.z); o[7]=f2b(b.w);
  *(u16x8*)(y + i*8) = o;
}

// ------------------------------------------- W[K][N] f32 -> Wt[N][K] bf16 (x4 fused)
__global__ void transpose_w_kernel(const float* __restrict__ W0, const float* __restrict__ W1,
                                   const float* __restrict__ W2, const float* __restrict__ W3,
                                   unsigned short* __restrict__ T0, unsigned short* __restrict__ T1,
                                   unsigned short* __restrict__ T2, unsigned short* __restrict__ T3){
  __shared__ float tile[32][33];
  const int z = blockIdx.z;
  const float* W = z==0 ? W0 : z==1 ? W1 : z==2 ? W2 : W3;
  unsigned short* Wt = z==0 ? T0 : z==1 ? T1 : z==2 ? T2 : T3;
  int tx = threadIdx.x, ty = threadIdx.y;
  int x0 = blockIdx.x*32, y0 = blockIdx.y*32;
  #pragma unroll
  for (int i=0;i<4;i++)
    tile[ty + i*8][tx] = W[(size_t)(y0 + ty + i*8)*D_MODEL + x0 + tx];
  __syncthreads();
  #pragma unroll
  for (int i=0;i<4;i++)
    Wt[(size_t)(x0 + ty + i*8)*D_MODEL + y0 + tx] = f2b(tile[tx][ty + i*8]);
}

// ---------------------------------------------------------------- GEMM (B^T form)
// C[M][N] = A[M][K] * Bt[N][K]^T + bias, A/Bt bf16, BK=64, global_load_lds staging.
// mode 0: bf16 row-major out. mode 1: V-transposed Vt[b][h][d][t] bf16. mode 2: f32.
__device__ __forceinline__ void gemm_body(const unsigned short* __restrict__ A,
                                          const unsigned short* __restrict__ Bt,
                                          const float* __restrict__ bias,
                                          void* __restrict__ Cout, const int mode,
                                          const int m0, const int n0)
{
  constexpr int K = D_MODEL, N = D_MODEL;
  __shared__ unsigned short As[128*64];   // 16KB, 128B rows, LINEAR (swizzle via source)
  __shared__ unsigned short Bs[128*64];   // 16KB
  const int t = threadIdx.x, lane = t&63, w = t>>6;
  const int wr = w>>1, wc = w&1, lr = lane&15, lg = lane>>4;
  // staging: lane l stages 16B chunk; source chunk index pre-swizzled so that
  // LDS[r*128 + u*16] holds global chunk (r, u^(r&7))  (rule #21 involution)
  const int osrc = (lane&7) ^ (lane>>3);
  f32x4 acc[4][4] = {};
  for (int k0 = 0; k0 < K; k0 += 64){
    __syncthreads();   // previous iter's frag reads done before re-staging
    #pragma unroll
    for (int g=0; g<4; g++){
      int reg = w*4 + g;                 // LDS region (8 rows x 128B = 1KB)
      int r = reg*8 + (lane>>3);         // tile row this lane sources
      gload16(A  + (size_t)(m0+r)*K + k0 + osrc*8, (char*)As + reg*1024);
      gload16(Bt + (size_t)(n0+r)*K + k0 + osrc*8, (char*)Bs + reg*1024);
    }
    __syncthreads();   // compiler drains vmcnt(0) before barrier
    #pragma unroll
    for (int ks=0; ks<2; ks++){
      bf16x8 af[4], bfv[4];
      #pragma unroll
      for (int mi=0;mi<4;mi++){
        int r = wr*64 + mi*16 + lr;
        af[mi] = *(const bf16x8*)((const char*)As + r*128 + (((ks*4+lg) ^ (r&7))*16));
      }
      #pragma unroll
      for (int ni=0;ni<4;ni++){
        int r = wc*64 + ni*16 + lr;
        bfv[ni] = *(const bf16x8*)((const char*)Bs + r*128 + (((ks*4+lg) ^ (r&7))*16));
      }
      #pragma unroll
      for (int mi=0;mi<4;mi++)
        #pragma unroll
        for (int ni=0;ni<4;ni++)
          acc[mi][ni] = mfma16(af[mi], bfv[ni], acc[mi][ni]);
    }
  }
  // epilogue: C/D frag mapping col=lane&15, row=(lane>>4)*4+reg
  #pragma unroll
  for (int mi=0;mi<4;mi++){
    #pragma unroll
    for (int ni=0;ni<4;ni++){
      int n = n0 + wc*64 + ni*16 + lr;
      int mbase = m0 + wr*64 + mi*16 + lg*4;
      float bv = bias[n];
      if (mode == 2){
        float* Cf = (float*)Cout;
        #pragma unroll
        for (int r=0;r<4;r++) Cf[(size_t)(mbase+r)*N + n] = acc[mi][ni][r] + bv;
      } else if (mode == 0){
        unsigned short* Cb = (unsigned short*)Cout;
        #pragma unroll
        for (int r=0;r<4;r++) Cb[(size_t)(mbase+r)*N + n] = f2b(acc[mi][ni][r] + bv);
      } else {
        unsigned short* Vt = (unsigned short*)Cout;
        int h = n >> 6, d = n & 63;
        int b = mbase >> 11;          // / TT
        int tq = mbase & (TT-1);
        u16x4 vv;
        #pragma unroll
        for (int r=0;r<4;r++) vv[r] = f2b(acc[mi][ni][r] + bv);
        *(u16x4*)(Vt + ((size_t)((b*NHEAD + h)*HDIM + d))*TT + tq) = vv;
      }
    }
  }
}

// proj: flat grid 768 = 8 xcd x 8 n x 4 m_inner x 3 z; all 8 n-blocks of one
// (m,z) A-panel share id%8 -> same XCD -> A-panel served from that L2. (T1)
__launch_bounds__(256)
__global__ void proj_gemm_kernel(const unsigned short* __restrict__ Xq,
                                 const unsigned short* __restrict__ Xk,
                                 const unsigned short* __restrict__ Xv,
                                 const unsigned short* __restrict__ Wtq,
                                 const unsigned short* __restrict__ Wtk,
                                 const unsigned short* __restrict__ Wtv,
                                 const float* __restrict__ b_q, const float* __restrict__ b_k,
                                 const float* __restrict__ b_v,
                                 unsigned short* __restrict__ Qb, unsigned short* __restrict__ Kb,
                                 unsigned short* __restrict__ Vt)
{
  const int id = blockIdx.x;
  const int xcd = id & 7, r2 = id >> 3;
  const int n = r2 & 7, mz = r2 >> 3;
  const int m = (mz & 3)*8 + xcd, z = mz >> 2;
  const unsigned short* A  = z==0 ? Xq : z==1 ? Xk : Xv;
  const unsigned short* Bt = z==0 ? Wtq : z==1 ? Wtk : Wtv;
  const float* bias = z==0 ? b_q : z==1 ? b_k : b_v;
  void* C = z==0 ? (void*)Qb : z==1 ? (void*)Kb : (void*)Vt;
  gemm_body(A, Bt, bias, C, z==2 ? 1 : 0, m*128, n*128);
}

__launch_bounds__(256)
__global__ void out_gemm_kernel(const unsigned short* __restrict__ Ob,
                                const unsigned short* __restrict__ Wto,
                                const float* __restrict__ b_o, float* __restrict__ out)
{
  const int id = blockIdx.x;
  const int xcd = id & 7, r2 = id >> 3;
  const int n = r2 & 7, m = (r2 >> 3)*8 + xcd;
  gemm_body(Ob, Wto, b_o, out, 2, m*128, n*128);
}

// ------------------------------------------------------- Pass A: column sums
// partialS[qc][bh][col] = sum_{q in 256-chunk qc, q>=col} exp(S[q,col])
__launch_bounds__(256)
__global__ void col_stats_kernel(const unsigned short* __restrict__ Qb,
                                 const unsigned short* __restrict__ Kb,
                                 float* __restrict__ partialS)
{
  __shared__ unsigned short Ks[128*64];   // 16KB
  __shared__ unsigned short Qs[64*64];    // 8KB
  const int t = threadIdx.x, lane = t&63, w = t>>6;
  const int id = blockIdx.x;
  const int bh = id & 31, pair = id >> 5;   // XCD = bh%8 -> per-bh L2 locality
  const int kb_ = pair & 15, qc = pair >> 4;
  const int b = bh >> 4, h = bh & 15;
  const int k0 = kb_ * 128;
  const int lr = lane&15, lg = lane>>4;
  #pragma unroll
  for (int i=0;i<4;i++){
    int c = i*256 + t; int r = c>>3, o = c&7;
    uint4 vv = *(const uint4*)(Kb + ((size_t)(b*TT + k0 + r))*D_MODEL + h*64 + o*8);
    *(uint4*)((char*)Ks + SWZ(r*128 + o*16, r)) = vv;
  }
  __syncthreads();
  bf16x8 bk[2][2];
  #pragma unroll
  for (int kb=0;kb<2;kb++)
    #pragma unroll
    for (int ks=0;ks<2;ks++){
      int r = w*32 + kb*16 + lr;
      bk[kb][ks] = *(const bf16x8*)((const char*)Ks + SWZ(r*128 + ks*64 + lg*16, r));
    }
  f32x4 sacc[2] = {};
  const int qstart = (k0 > qc*256) ? k0 : qc*256;
  const int qend   = (qc+1)*256;
  for (int qt = qstart; qt < qend; qt += 64){
    __syncthreads();
    #pragma unroll
    for (int i=0;i<2;i++){
      int c = i*256 + t; int r = c>>3, o = c&7;
      uint4 vv = *(const uint4*)(Qb + ((size_t)(b*TT + qt + r))*D_MODEL + h*64 + o*8);
      *(uint4*)((char*)Qs + SWZ(r*128 + o*16, r)) = vv;
    }
    __syncthreads();
    const bool interior = (qt >= k0 + 128);
    #pragma unroll
    for (int qb=0;qb<4;qb++){
      bf16x8 aq[2];
      #pragma unroll
      for (int ks=0;ks<2;ks++){
        int r = qb*16 + lr;
        aq[ks] = *(const bf16x8*)((const char*)Qs + SWZ(r*128 + ks*64 + lg*16, r));
      }
      f32x4 sf[2] = {};
      #pragma unroll
      for (int ks=0;ks<2;ks++)
        #pragma unroll
        for (int kb=0;kb<2;kb++)
          sf[kb] = mfma16(aq[ks], bk[kb][ks], sf[kb]);
      #pragma unroll
      for (int kb=0;kb<2;kb++){
        int col = k0 + w*32 + kb*16 + lr;
        #pragma unroll
        for (int r=0;r<4;r++){
          float e = __expf(sf[kb][r] * 0.125f);
          if (!interior){
            int qg = qt + qb*16 + lg*4 + r;
            e = (qg >= col) ? e : 0.f;
          }
          sacc[kb][r] += e;
        }
      }
    }
  }
  #pragma unroll
  for (int kb=0;kb<2;kb++){
    float s = sacc[kb][0] + sacc[kb][1] + sacc[kb][2] + sacc[kb][3];
    s += __shfl_xor(s, 16);
    s += __shfl_xor(s, 32);
    if (lg == 0){
      int col = k0 + w*32 + kb*16 + lr;
      partialS[((size_t)qc*BHN + bh)*TT + col] = s;
    }
  }
}

__global__ void col_combine_kernel(const float* __restrict__ partialS, float* __restrict__ colS){
  int i = blockIdx.x*256 + threadIdx.x;
  float s = 0.f;
  #pragma unroll
  for (int qc=0;qc<8;qc++) s += partialS[(size_t)qc*BHN*TT + i];
  colS[i] = 1.0f / s;
}

// ------------------------------------------------------------- Pass B: output
__launch_bounds__(256)
__global__ void attn_out_kernel(const unsigned short* __restrict__ Qb,
                                const unsigned short* __restrict__ Kb,
                                const unsigned short* __restrict__ Vt,
                                const float* __restrict__ colS,
                                unsigned short* __restrict__ O)
{
  __shared__ unsigned short Qs[64*64];
  __shared__ unsigned short Ks2[64*64];
  __shared__ unsigned short Vs[64*64];
  __shared__ unsigned short Ps[64*64];
  const int t = threadIdx.x, lane=t&63, w=t>>6;
  const int id = blockIdx.x;
  const int bh = id & 31;
  const int qi = 31 - (id >> 5);          // heavy blocks first
  const int b = bh>>4, h = bh&15;
  const int q0 = qi*64;
  const int lr = lane&15, lg = lane>>4;
  #pragma unroll
  for (int i=0;i<2;i++){
    int c = i*256+t; int r=c>>3, o=c&7;
    uint4 vv = *(const uint4*)(Qb + ((size_t)(b*TT + q0 + r))*D_MODEL + h*64 + o*8);
    *(uint4*)((char*)Qs + SWZ(r*128 + o*16, r)) = vv;
  }
  __syncthreads();
  bf16x8 aq[2];
  #pragma unroll
  for (int ks=0;ks<2;ks++){
    int r = w*16 + lr;
    aq[ks] = *(const bf16x8*)((const char*)Qs + SWZ(r*128 + ks*64 + lg*16, r));
  }
  f32x4 oacc[4] = {};
  const int nkt = qi + 1;
  for (int kt=0; kt<nkt; kt++){
    int k0 = kt*64;
    __syncthreads();
    #pragma unroll
    for (int i=0;i<2;i++){
      int c = i*256+t; int r=c>>3, o=c&7;
      uint4 vk = *(const uint4*)(Kb + ((size_t)(b*TT + k0 + r))*D_MODEL + h*64 + o*8);
      uint4 vv = *(const uint4*)(Vt + ((size_t)(bh*HDIM + r))*TT + k0 + o*8);
      int byte = SWZ(r*128 + o*16, r);
      *(uint4*)((char*)Ks2 + byte) = vk;
      *(uint4*)((char*)Vs  + byte) = vv;
    }
    __syncthreads();
    f32x4 sf[4] = {};
    #pragma unroll
    for (int ks=0;ks<2;ks++)
      #pragma unroll
      for (int kb=0;kb<4;kb++){
        int r = kb*16 + lr;
        bf16x8 bk = *(const bf16x8*)((const char*)Ks2 + SWZ(r*128 + ks*64 + lg*16, r));
        sf[kb] = mfma16(aq[ks], bk, sf[kb]);
      }
    const bool boundary = (kt == qi);
    #pragma unroll
    for (int kb=0;kb<4;kb++){
      int col = k0 + kb*16 + lr;
      float isc = colS[(size_t)bh*TT + col];
      #pragma unroll
      for (int r=0;r<4;r++){
        int prow = w*16 + lg*4 + r;
        float pv = __expf(sf[kb][r]*0.125f) * isc;
        if (boundary){
          int qg = q0 + prow;
          pv = (qg >= col) ? pv : 0.f;
        }
        *(unsigned short*)((char*)Ps + SWZ((prow*64 + kb*16 + lr)*2, prow)) = f2b(pv);
      }
    }
    #pragma unroll
    for (int ks=0;ks<2;ks++){
      int pr = w*16 + lr;
      bf16x8 pa = *(const bf16x8*)((const char*)Ps + SWZ(pr*128 + ks*64 + lg*16, pr));
      #pragma unroll
      for (int db=0;db<4;db++){
        int r = db*16 + lr;
        bf16x8 bv = *(const bf16x8*)((const char*)Vs + SWZ(r*128 + ks*64 + lg*16, r));
        oacc[db] = mfma16(pa, bv, oacc[db]);
      }
    }
  }
  #pragma unroll
  for (int db=0;db<4;db++){
    int qg = q0 + w*16 + lg*4;
    int d  = db*16 + lr;
    #pragma unroll
    for (int r=0;r<4;r++)
      O[((size_t)(b*TT + qg + r))*D_MODEL + h*64 + d] = f2b(oacc[db][r]);
  }
}

// ---------------------------------------------------------------------- launch
extern "C" void kernel_launch(void* const* d_in, const int* in_sizes, int n_in,
                              void* d_out, int out_size, void* d_ws, size_t ws_size,
                              hipStream_t stream)
{
  (void)in_sizes; (void)n_in; (void)out_size; (void)ws_size;
  const float* q   = (const float*)d_in[0];
  const float* k   = (const float*)d_in[1];
  const float* v   = (const float*)d_in[2];
  const float* w_q = (const float*)d_in[3];
  const float* b_q = (const float*)d_in[4];
  const float* w_k = (const float*)d_in[5];
  const float* b_k = (const float*)d_in[6];
  const float* w_v = (const float*)d_in[7];
  const float* b_v = (const float*)d_in[8];
  const float* w_o = (const float*)d_in[9];
  const float* b_o = (const float*)d_in[10];

  char* p = (char*)d_ws;
  auto carve = [&](size_t bytes)->char* {
    char* r = p; p += (bytes + 255) & ~(size_t)255; return r;
  };
  unsigned short* Xq  = (unsigned short*)carve((size_t)MM*D_MODEL*2);
  unsigned short* Xk  = (unsigned short*)carve((size_t)MM*D_MODEL*2);
  unsigned short* Xv  = (unsigned short*)carve((size_t)MM*D_MODEL*2);
  unsigned short* Wtq = (unsigned short*)carve((size_t)D_MODEL*D_MODEL*2);
  unsigned short* Wtk = (unsigned short*)carve((size_t)D_MODEL*D_MODEL*2);
  unsigned short* Wtv = (unsigned short*)carve((size_t)D_MODEL*D_MODEL*2);
  unsigned short* Wto = (unsigned short*)carve((size_t)D_MODEL*D_MODEL*2);
  unsigned short* Qb  = (unsigned short*)carve((size_t)MM*D_MODEL*2);
  unsigned short* Kb  = (unsigned short*)carve((size_t)MM*D_MODEL*2);
  unsigned short* Vt  = (unsigned short*)carve((size_t)MM*D_MODEL*2);
  unsigned short* Ob  = (unsigned short*)carve((size_t)MM*D_MODEL*2);
  float* partialS = (float*)carve((size_t)8*BHN*TT*4);
  float* colS     = (float*)carve((size_t)BHN*TT*4);

  cvt_bf16_kernel<<<dim3((MM*D_MODEL/8)/256, 3), 256, 0, stream>>>(q, k, v, Xq, Xk, Xv);

  dim3 tgrid(32,32,4), tblk(32,8);
  transpose_w_kernel<<<tgrid, tblk, 0, stream>>>(w_q, w_k, w_v, w_o, Wtq, Wtk, Wtv, Wto);

  proj_gemm_kernel<<<dim3(768), 256, 0, stream>>>(Xq, Xk, Xv, Wtq, Wtk, Wtv,
                                                  b_q, b_k, b_v, Qb, Kb, Vt);

  col_stats_kernel<<<dim3(8*16*BHN), 256, 0, stream>>>(Qb, Kb, partialS);
  col_combine_kernel<<<dim3(BHN*TT/256), 256, 0, stream>>>(partialS, colS);

  attn_out_kernel<<<dim3((TT/64)*BHN), 256, 0, stream>>>(Qb, Kb, Vt, colS, Ob);

  out_gemm_kernel<<<dim3(256), 256, 0, stream>>>(Ob, Wto, b_o, (float*)d_out);
}

// Round 5
// 143.906 us; speedup vs baseline: 2.7158x; 1.1616x over previous
//
#include <hip/hip_runtime.h>
#include <hip/hip_bf16.h>
#include <cstdint>
#include <cstddef>

#define D_MODEL 1024
#define NHEAD   16
#define HDIM    64
#define BB      2
#define TT      2048
#define MM      (BB*TT)    // 4096 rows
#define BHN     (BB*NHEAD) // 32

typedef __attribute__((ext_vector_type(8))) __bf16 bf16x8;
typedef __attribute__((ext_vector_type(4))) float  f32x4;
typedef __attribute__((ext_vector_type(8))) unsigned short u16x8;
typedef __attribute__((ext_vector_type(4))) unsigned short u16x4;

__device__ __forceinline__ unsigned short f2b(float f){
  __bf16 b = (__bf16)f;
  return __builtin_bit_cast(unsigned short, b);
}
__device__ __forceinline__ float b2f(unsigned short u){
  unsigned int x = ((unsigned int)u) << 16;
  return __builtin_bit_cast(float, x);
}

__device__ __forceinline__ f32x4 mfma16(bf16x8 a, bf16x8 b, f32x4 c){
  return __builtin_amdgcn_mfma_f32_16x16x32_bf16(a, b, c, 0, 0, 0);
}

// async global->LDS, 16B per lane; LDS dest = base + lane*16 (linear).
__device__ __forceinline__ void gload16(const void* g, void* lds){
  __builtin_amdgcn_global_load_lds((const __attribute__((address_space(1))) void*)g,
                                   (__attribute__((address_space(3))) void*)lds, 16, 0, 0);
}

// XOR swizzle on logical byte offsets of 128B-row LDS tiles (bits 4-6 ^ row&7).
// Writes (or pre-swizzled gload sources) and reads must both apply it.
#define SWZ(byteoff, row) ((byteoff) ^ (((row)&7)<<4))

// ------------------------------------------------- cvt f32 -> bf16 (q,k,v fused)
__global__ void cvt_bf16_kernel(const float* __restrict__ q, const float* __restrict__ k,
                                const float* __restrict__ v,
                                unsigned short* __restrict__ Xq, unsigned short* __restrict__ Xk,
                                unsigned short* __restrict__ Xv){
  const int z = blockIdx.y;
  const float* x = z==0 ? q : z==1 ? k : v;
  unsigned short* y = z==0 ? Xq : z==1 ? Xk : Xv;
  size_t i = (size_t)blockIdx.x*blockDim.x + threadIdx.x;
  const float4* p = (const float4*)(x + i*8);
  float4 a = p[0], b = p[1];
  u16x8 o;
  o[0]=f2b(a.x); o[1]=f2b(a.y); o[2]=f2b(a.z); o[3]=f2b(a.w);
  o[4]=f2b(b.x); o[5]=f2b(b.y); o[6]=f2b(b.z); o[7]=f2b(b.w);
  *(u16x8*)(y + i*8) = o;
}

// ------------------------------------------- W[K][N] f32 -> Wt[N][K] bf16 (x4 fused)
__global__ void transpose_w_kernel(const float* __restrict__ W0, const float* __restrict__ W1,
                                   const float* __restrict__ W2, const float* __restrict__ W3,
                                   unsigned short* __restrict__ T0, unsigned short* __restrict__ T1,
                                   unsigned short* __restrict__ T2, unsigned short* __restrict__ T3){
  __shared__ float tile[32][33];
  const int z = blockIdx.z;
  const float* W = z==0 ? W0 : z==1 ? W1 : z==2 ? W2 : W3;
  unsigned short* Wt = z==0 ? T0 : z==1 ? T1 : z==2 ? T2 : T3;
  int tx = threadIdx.x, ty = threadIdx.y;
  int x0 = blockIdx.x*32, y0 = blockIdx.y*32;
  #pragma unroll
  for (int i=0;i<4;i++)
    tile[ty + i*8][tx] = W[(size_t)(y0 + ty + i*8)*D_MODEL + x0 + tx];
  __syncthreads();
  #pragma unroll
  for (int i=0;i<4;i++)
    Wt[(size_t)(x0 + ty + i*8)*D_MODEL + y0 + tx] = f2b(tile[tx][ty + i*8]);
}

// ---------------------------------------------------------------- GEMM (B^T form)
// C[M][N] = A[M][K] * Bt[N][K]^T + bias, 128x128 tile, BK=64, gload16 staging.
// mode 0: bf16 row-major out. mode 1: V-transposed Vt[b][h][d][t] bf16.
__device__ __forceinline__ void gemm_body(const unsigned short* __restrict__ A,
                                          const unsigned short* __restrict__ Bt,
                                          const float* __restrict__ bias,
                                          void* __restrict__ Cout, const int mode,
                                          const int m0, const int n0)
{
  constexpr int K = D_MODEL, N = D_MODEL;
  __shared__ unsigned short As[128*64];   // 16KB, linear; swizzle via source chunk
  __shared__ unsigned short Bs[128*64];   // 16KB
  const int t = threadIdx.x, lane = t&63, w = t>>6;
  const int wr = w>>1, wc = w&1, lr = lane&15, lg = lane>>4;
  const int osrc = (lane&7) ^ (lane>>3);  // involution: LDS[r][u] = G[r][u^(r&7)]
  f32x4 acc[4][4] = {};
  for (int k0 = 0; k0 < K; k0 += 64){
    __syncthreads();
    #pragma unroll
    for (int g=0; g<4; g++){
      int reg = w*4 + g;                 // 1KB region = 8 rows
      int r = reg*8 + (lane>>3);
      gload16(A  + (size_t)(m0+r)*K + k0 + osrc*8, (char*)As + reg*1024);
      gload16(Bt + (size_t)(n0+r)*K + k0 + osrc*8, (char*)Bs + reg*1024);
    }
    __syncthreads();
    #pragma unroll
    for (int ks=0; ks<2; ks++){
      bf16x8 af[4], bfv[4];
      #pragma unroll
      for (int mi=0;mi<4;mi++){
        int r = wr*64 + mi*16 + lr;
        af[mi] = *(const bf16x8*)((const char*)As + r*128 + (((ks*4+lg) ^ (r&7))*16));
      }
      #pragma unroll
      for (int ni=0;ni<4;ni++){
        int r = wc*64 + ni*16 + lr;
        bfv[ni] = *(const bf16x8*)((const char*)Bs + r*128 + (((ks*4+lg) ^ (r&7))*16));
      }
      #pragma unroll
      for (int mi=0;mi<4;mi++)
        #pragma unroll
        for (int ni=0;ni<4;ni++)
          acc[mi][ni] = mfma16(af[mi], bfv[ni], acc[mi][ni]);
    }
  }
  #pragma unroll
  for (int mi=0;mi<4;mi++){
    #pragma unroll
    for (int ni=0;ni<4;ni++){
      int n = n0 + wc*64 + ni*16 + lr;
      int mbase = m0 + wr*64 + mi*16 + lg*4;
      float bv = bias[n];
      if (mode == 0){
        unsigned short* Cb = (unsigned short*)Cout;
        #pragma unroll
        for (int r=0;r<4;r++) Cb[(size_t)(mbase+r)*N + n] = f2b(acc[mi][ni][r] + bv);
      } else {
        unsigned short* Vt = (unsigned short*)Cout;
        int h = n >> 6, d = n & 63;
        int b = mbase >> 11;
        int tq = mbase & (TT-1);
        u16x4 vv;
        #pragma unroll
        for (int r=0;r<4;r++) vv[r] = f2b(acc[mi][ni][r] + bv);
        *(u16x4*)(Vt + ((size_t)((b*NHEAD + h)*HDIM + d))*TT + tq) = vv;
      }
    }
  }
}

// proj: flat grid 768 = 8 xcd x 8 n x 4 m_inner x 3 z (T1 XCD-locality for A-panels)
__launch_bounds__(256)
__global__ void proj_gemm_kernel(const unsigned short* __restrict__ Xq,
                                 const unsigned short* __restrict__ Xk,
                                 const unsigned short* __restrict__ Xv,
                                 const unsigned short* __restrict__ Wtq,
                                 const unsigned short* __restrict__ Wtk,
                                 const unsigned short* __restrict__ Wtv,
                                 const float* __restrict__ b_q, const float* __restrict__ b_k,
                                 const float* __restrict__ b_v,
                                 unsigned short* __restrict__ Qb, unsigned short* __restrict__ Kb,
                                 unsigned short* __restrict__ Vt)
{
  const int id = blockIdx.x;
  const int xcd = id & 7, r2 = id >> 3;
  const int n = r2 & 7, mz = r2 >> 3;
  const int m = (mz & 3)*8 + xcd, z = mz >> 2;
  const unsigned short* A  = z==0 ? Xq : z==1 ? Xk : Xv;
  const unsigned short* Bt = z==0 ? Wtq : z==1 ? Wtk : Wtv;
  const float* bias = z==0 ? b_q : z==1 ? b_k : b_v;
  void* C = z==0 ? (void*)Qb : z==1 ? (void*)Kb : (void*)Vt;
  gemm_body(A, Bt, bias, C, z==2 ? 1 : 0, m*128, n*128);
}

// out-proj: 64x128 tiles, 512 blocks (2/CU), f32 output
__launch_bounds__(256)
__global__ void out_gemm_kernel(const unsigned short* __restrict__ Ob,
                                const unsigned short* __restrict__ Wto,
                                const float* __restrict__ b_o, float* __restrict__ out)
{
  constexpr int K = D_MODEL, N = D_MODEL;
  __shared__ unsigned short As[64*64];    // 8KB
  __shared__ unsigned short Bs[128*64];   // 16KB
  const int id = blockIdx.x;
  const int xcd = id & 7, r2 = id >> 3;
  const int n0 = (r2 & 7)*128, m0 = ((r2 >> 3)*8 + xcd)*64;
  const int t = threadIdx.x, lane = t&63, w = t>>6;
  const int wr = w>>1, wc = w&1, lr = lane&15, lg = lane>>4;
  const int osrc = (lane&7) ^ (lane>>3);
  f32x4 acc[2][4] = {};
  for (int k0 = 0; k0 < K; k0 += 64){
    __syncthreads();
    #pragma unroll
    for (int g=0; g<2; g++){
      int reg = w*2 + g;
      int r = reg*8 + (lane>>3);
      gload16(Ob + (size_t)(m0+r)*K + k0 + osrc*8, (char*)As + reg*1024);
    }
    #pragma unroll
    for (int g=0; g<4; g++){
      int reg = w*4 + g;
      int r = reg*8 + (lane>>3);
      gload16(Wto + (size_t)(n0+r)*K + k0 + osrc*8, (char*)Bs + reg*1024);
    }
    __syncthreads();
    #pragma unroll
    for (int ks=0; ks<2; ks++){
      bf16x8 af[2], bfv[4];
      #pragma unroll
      for (int mi=0;mi<2;mi++){
        int r = wr*32 + mi*16 + lr;
        af[mi] = *(const bf16x8*)((const char*)As + r*128 + (((ks*4+lg) ^ (r&7))*16));
      }
      #pragma unroll
      for (int ni=0;ni<4;ni++){
        int r = wc*64 + ni*16 + lr;
        bfv[ni] = *(const bf16x8*)((const char*)Bs + r*128 + (((ks*4+lg) ^ (r&7))*16));
      }
      #pragma unroll
      for (int mi=0;mi<2;mi++)
        #pragma unroll
        for (int ni=0;ni<4;ni++)
          acc[mi][ni] = mfma16(af[mi], bfv[ni], acc[mi][ni]);
    }
  }
  #pragma unroll
  for (int mi=0;mi<2;mi++){
    #pragma unroll
    for (int ni=0;ni<4;ni++){
      int n = n0 + wc*64 + ni*16 + lr;
      int mbase = m0 + wr*32 + mi*16 + lg*4;
      float bv = b_o[n];
      #pragma unroll
      for (int r=0;r<4;r++) out[(size_t)(mbase+r)*N + n] = acc[mi][ni][r] + bv;
    }
  }
}

// ------------------------------------------------------- Pass A: column sums
// partialS[qc][bh][col] = sum_{q in 256-chunk qc, q>=col} exp(S[q,col])
__launch_bounds__(256)
__global__ void col_stats_kernel(const unsigned short* __restrict__ Qb,
                                 const unsigned short* __restrict__ Kb,
                                 float* __restrict__ partialS)
{
  __shared__ unsigned short Ks[128*64];   // 16KB, linear + src-swizzled
  __shared__ unsigned short Qs[64*64];    // 8KB
  const int t = threadIdx.x, lane = t&63, w = t>>6;
  const int id = blockIdx.x;
  const int bh = id & 31, pair = id >> 5;   // XCD = bh%8 -> per-bh L2 locality
  const int kb_ = pair & 15, qc = pair >> 4;
  const int b = bh >> 4, h = bh & 15;
  const int k0 = kb_ * 128;
  const int lr = lane&15, lg = lane>>4;
  const int osrc = (lane&7) ^ (lane>>3);
  #pragma unroll
  for (int g=0; g<4; g++){
    int reg = w*4 + g;
    int r = reg*8 + (lane>>3);
    gload16(Kb + ((size_t)(b*TT + k0 + r))*D_MODEL + h*64 + osrc*8, (char*)Ks + reg*1024);
  }
  __syncthreads();
  bf16x8 bk[2][2];
  #pragma unroll
  for (int kb=0;kb<2;kb++)
    #pragma unroll
    for (int ks=0;ks<2;ks++){
      int r = w*32 + kb*16 + lr;
      bk[kb][ks] = *(const bf16x8*)((const char*)Ks + r*128 + (((ks*4+lg) ^ (r&7))*16));
    }
  f32x4 sacc[2] = {};
  const int qstart = (k0 > qc*256) ? k0 : qc*256;
  const int qend   = (qc+1)*256;
  for (int qt = qstart; qt < qend; qt += 64){
    __syncthreads();
    #pragma unroll
    for (int g=0; g<2; g++){
      int reg = w*2 + g;
      int r = reg*8 + (lane>>3);
      gload16(Qb + ((size_t)(b*TT + qt + r))*D_MODEL + h*64 + osrc*8, (char*)Qs + reg*1024);
    }
    __syncthreads();
    const bool interior = (qt >= k0 + 128);
    #pragma unroll
    for (int qb=0;qb<4;qb++){
      bf16x8 aq[2];
      #pragma unroll
      for (int ks=0;ks<2;ks++){
        int r = qb*16 + lr;
        aq[ks] = *(const bf16x8*)((const char*)Qs + r*128 + (((ks*4+lg) ^ (r&7))*16));
      }
      f32x4 sf[2] = {};
      #pragma unroll
      for (int ks=0;ks<2;ks++)
        #pragma unroll
        for (int kb=0;kb<2;kb++)
          sf[kb] = mfma16(aq[ks], bk[kb][ks], sf[kb]);
      #pragma unroll
      for (int kb=0;kb<2;kb++){
        int col = k0 + w*32 + kb*16 + lr;
        #pragma unroll
        for (int r=0;r<4;r++){
          float e = __expf(sf[kb][r] * 0.125f);
          if (!interior){
            int qg = qt + qb*16 + lg*4 + r;
            e = (qg >= col) ? e : 0.f;
          }
          sacc[kb][r] += e;
        }
      }
    }
  }
  #pragma unroll
  for (int kb=0;kb<2;kb++){
    float s = sacc[kb][0] + sacc[kb][1] + sacc[kb][2] + sacc[kb][3];
    s += __shfl_xor(s, 16);
    s += __shfl_xor(s, 32);
    if (lg == 0){
      int col = k0 + w*32 + kb*16 + lr;
      partialS[((size_t)qc*BHN + bh)*TT + col] = s;
    }
  }
}

__global__ void col_combine_kernel(const float* __restrict__ partialS, float* __restrict__ colS){
  int i = blockIdx.x*256 + threadIdx.x;
  float s = 0.f;
  #pragma unroll
  for (int qc=0;qc<8;qc++) s += partialS[(size_t)qc*BHN*TT + i];
  colS[i] = 1.0f / s;
}

// ---------------------------------------- V' = V * invs_k  (fold normalizer into V)
__global__ void vscale_kernel(unsigned short* __restrict__ Vt, const float* __restrict__ colS){
  size_t c = (size_t)blockIdx.x*256 + threadIdx.x;  // chunk of 8 t-values
  int t0  = (int)(c & 255) * 8;
  int row = (int)(c >> 8);            // bh*64 + d
  int bh  = row >> 6;
  u16x8 v = *(u16x8*)(Vt + (size_t)row*TT + t0);
  const float4* cs = (const float4*)(colS + (size_t)bh*TT + t0);
  float4 s0 = cs[0], s1 = cs[1];
  v[0]=f2b(b2f(v[0])*s0.x); v[1]=f2b(b2f(v[1])*s0.y);
  v[2]=f2b(b2f(v[2])*s0.z); v[3]=f2b(b2f(v[3])*s0.w);
  v[4]=f2b(b2f(v[4])*s1.x); v[5]=f2b(b2f(v[5])*s1.y);
  v[6]=f2b(b2f(v[6])*s1.z); v[7]=f2b(b2f(v[7])*s1.w);
  *(u16x8*)(Vt + (size_t)row*TT + t0) = v;
}

// ------------------------------------------------------------- Pass B: output
// O[q,:] = sum_{k<=q} exp(S[q,k]) * V'[k,:]  (V' pre-scaled by invs_k)
// Swapped QK^T (S^T = K.Q^T): lane holds contiguous k-runs -> b64 P writes.
__launch_bounds__(256)
__global__ void attn_out_kernel(const unsigned short* __restrict__ Qb,
                                const unsigned short* __restrict__ Kb,
                                const unsigned short* __restrict__ Vt,
                                unsigned short* __restrict__ O)
{
  __shared__ unsigned short Qs[64*64];    // 8KB, linear + src-swizzle
  __shared__ unsigned short Ks2[64*64];   // 8KB
  __shared__ unsigned short Vs[64*64];    // 8KB
  __shared__ unsigned short Ps[64*64];    // 8KB (wave-private 16-row strips)
  const int t = threadIdx.x, lane=t&63, w=t>>6;
  const int id = blockIdx.x;
  const int bh = id & 31;                 // XCD = bh%8 -> K/V in one XCD's L2
  const int qi = 31 - (id >> 5);          // heavy blocks first
  const int b = bh>>4, h = bh&15;
  const int q0 = qi*64;
  const int lr = lane&15, lg = lane>>4;
  const int osrc = (lane&7) ^ (lane>>3);
  #pragma unroll
  for (int g=0; g<2; g++){
    int reg = w*2 + g;
    int r = reg*8 + (lane>>3);
    gload16(Qb + ((size_t)(b*TT + q0 + r))*D_MODEL + h*64 + osrc*8, (char*)Qs + reg*1024);
  }
  __syncthreads();
  bf16x8 aq[2];
  #pragma unroll
  for (int ks=0;ks<2;ks++){
    int r = w*16 + lr;
    aq[ks] = *(const bf16x8*)((const char*)Qs + r*128 + (((ks*4+lg) ^ (r&7))*16));
  }
  f32x4 oacc[4] = {};
  const int nkt = qi + 1;
  for (int kt=0; kt<nkt; kt++){
    int k0 = kt*64;
    __syncthreads();
    #pragma unroll
    for (int g=0; g<2; g++){
      int reg = w*2 + g;
      int r = reg*8 + (lane>>3);
      gload16(Kb + ((size_t)(b*TT + k0 + r))*D_MODEL + h*64 + osrc*8, (char*)Ks2 + reg*1024);
      gload16(Vt + ((size_t)(bh*HDIM + r))*TT + k0 + osrc*8, (char*)Vs + reg*1024);
    }
    __syncthreads();
    // S^T = K . Q^T : col = q (lane&15), row = k (lg*4 + r within 16-block)
    f32x4 sf[4] = {};
    #pragma unroll
    for (int ks=0;ks<2;ks++)
      #pragma unroll
      for (int kb=0;kb<4;kb++){
        int r = kb*16 + lr;
        bf16x8 bk = *(const bf16x8*)((const char*)Ks2 + r*128 + (((ks*4+lg) ^ (r&7))*16));
        sf[kb] = mfma16(bk, aq[ks], sf[kb]);   // SWAPPED operands
      }
    // P = exp(S) (unnormalized); contiguous k-run of 4 -> one b64 LDS write
    const bool boundary = (kt == qi);
    const int prow = w*16 + lr;
    #pragma unroll
    for (int kb=0;kb<4;kb++){
      u16x4 vv;
      #pragma unroll
      for (int r=0;r<4;r++){
        float pv = __expf(sf[kb][r]*0.125f);
        if (boundary){
          int kg = k0 + kb*16 + lg*4 + r;
          int qg = q0 + prow;
          pv = (qg >= kg) ? pv : 0.f;
        }
        vv[r] = f2b(pv);
      }
      *(u16x4*)((char*)Ps + SWZ(prow*128 + kb*32 + lg*8, prow)) = vv;
    }
    // (Ps rows wave-private; in-wave lgkmcnt ordering suffices)
    #pragma unroll
    for (int ks=0;ks<2;ks++){
      bf16x8 pa = *(const bf16x8*)((const char*)Ps + prow*128 + (((ks*4+lg) ^ (prow&7))*16));
      #pragma unroll
      for (int db=0;db<4;db++){
        int r = db*16 + lr;
        bf16x8 bv = *(const bf16x8*)((const char*)Vs + r*128 + (((ks*4+lg) ^ (r&7))*16));
        oacc[db] = mfma16(pa, bv, oacc[db]);
      }
    }
  }
  #pragma unroll
  for (int db=0;db<4;db++){
    int qg = q0 + w*16 + lg*4;
    int d  = db*16 + lr;
    #pragma unroll
    for (int r=0;r<4;r++)
      O[((size_t)(b*TT + qg + r))*D_MODEL + h*64 + d] = f2b(oacc[db][r]);
  }
}

// ---------------------------------------------------------------------- launch
extern "C" void kernel_launch(void* const* d_in, const int* in_sizes, int n_in,
                              void* d_out, int out_size, void* d_ws, size_t ws_size,
                              hipStream_t stream)
{
  (void)in_sizes; (void)n_in; (void)out_size; (void)ws_size;
  const float* q   = (const float*)d_in[0];
  const float* k   = (const float*)d_in[1];
  const float* v   = (const float*)d_in[2];
  const float* w_q = (const float*)d_in[3];
  const float* b_q = (const float*)d_in[4];
  const float* w_k = (const float*)d_in[5];
  const float* b_k = (const float*)d_in[6];
  const float* w_v = (const float*)d_in[7];
  const float* b_v = (const float*)d_in[8];
  const float* w_o = (const float*)d_in[9];
  const float* b_o = (const float*)d_in[10];

  char* p = (char*)d_ws;
  auto carve = [&](size_t bytes)->char* {
    char* r = p; p += (bytes + 255) & ~(size_t)255; return r;
  };
  unsigned short* Xq  = (unsigned short*)carve((size_t)MM*D_MODEL*2);
  unsigned short* Xk  = (unsigned short*)carve((size_t)MM*D_MODEL*2);
  unsigned short* Xv  = (unsigned short*)carve((size_t)MM*D_MODEL*2);
  unsigned short* Wtq = (unsigned short*)carve((size_t)D_MODEL*D_MODEL*2);
  unsigned short* Wtk = (unsigned short*)carve((size_t)D_MODEL*D_MODEL*2);
  unsigned short* Wtv = (unsigned short*)carve((size_t)D_MODEL*D_MODEL*2);
  unsigned short* Wto = (unsigned short*)carve((size_t)D_MODEL*D_MODEL*2);
  unsigned short* Qb  = (unsigned short*)carve((size_t)MM*D_MODEL*2);
  unsigned short* Kb  = (unsigned short*)carve((size_t)MM*D_MODEL*2);
  unsigned short* Vt  = (unsigned short*)carve((size_t)MM*D_MODEL*2);
  unsigned short* Ob  = (unsigned short*)carve((size_t)MM*D_MODEL*2);
  float* partialS = (float*)carve((size_t)8*BHN*TT*4);
  float* colS     = (float*)carve((size_t)BHN*TT*4);

  cvt_bf16_kernel<<<dim3((MM*D_MODEL/8)/256, 3), 256, 0, stream>>>(q, k, v, Xq, Xk, Xv);

  dim3 tgrid(32,32,4), tblk(32,8);
  transpose_w_kernel<<<tgrid, tblk, 0, stream>>>(w_q, w_k, w_v, w_o, Wtq, Wtk, Wtv, Wto);

  proj_gemm_kernel<<<dim3(768), 256, 0, stream>>>(Xq, Xk, Xv, Wtq, Wtk, Wtv,
                                                  b_q, b_k, b_v, Qb, Kb, Vt);

  col_stats_kernel<<<dim3(8*16*BHN), 256, 0, stream>>>(Qb, Kb, partialS);
  col_combine_kernel<<<dim3(BHN*TT/256), 256, 0, stream>>>(partialS, colS);

  vscale_kernel<<<dim3((BHN*HDIM*TT/8)/256), 256, 0, stream>>>(Vt, colS);

  attn_out_kernel<<<dim3((TT/64)*BHN), 256, 0, stream>>>(Qb, Kb, Vt, Ob);

  out_gemm_kernel<<<dim3(512), 256, 0, stream>>>(Ob, Wto, b_o, (float*)d_out);
}

// Round 6
// 140.664 us; speedup vs baseline: 2.7784x; 1.0230x over previous
//
#include <hip/hip_runtime.h>
#include <hip/hip_bf16.h>
#include <cstdint>
#include <cstddef>

#define D_MODEL 1024
#define NHEAD   16
#define HDIM    64
#define BB      2
#define TT      2048
#define MM      (BB*TT)    // 4096 rows
#define BHN     (BB*NHEAD) // 32

typedef __attribute__((ext_vector_type(8))) __bf16 bf16x8;
typedef __attribute__((ext_vector_type(4))) float  f32x4;
typedef __attribute__((ext_vector_type(8))) unsigned short u16x8;
typedef __attribute__((ext_vector_type(4))) unsigned short u16x4;

__device__ __forceinline__ unsigned short f2b(float f){
  __bf16 b = (__bf16)f;
  return __builtin_bit_cast(unsigned short, b);
}
__device__ __forceinline__ float b2f(unsigned short u){
  unsigned int x = ((unsigned int)u) << 16;
  return __builtin_bit_cast(float, x);
}

__device__ __forceinline__ f32x4 mfma16(bf16x8 a, bf16x8 b, f32x4 c){
  return __builtin_amdgcn_mfma_f32_16x16x32_bf16(a, b, c, 0, 0, 0);
}

// async global->LDS, 16B per lane; LDS dest = wave-uniform base + lane*16.
__device__ __forceinline__ void gload16(const void* g, void* lds){
  __builtin_amdgcn_global_load_lds((const __attribute__((address_space(1))) void*)g,
                                   (__attribute__((address_space(3))) void*)lds, 16, 0, 0);
}

// ------------------------------------------------- cvt f32 -> bf16 (q,k,v fused)
__global__ void cvt_bf16_kernel(const float* __restrict__ q, const float* __restrict__ k,
                                const float* __restrict__ v,
                                unsigned short* __restrict__ Xq, unsigned short* __restrict__ Xk,
                                unsigned short* __restrict__ Xv){
  const int z = blockIdx.y;
  const float* x = z==0 ? q : z==1 ? k : v;
  unsigned short* y = z==0 ? Xq : z==1 ? Xk : Xv;
  size_t i = (size_t)blockIdx.x*blockDim.x + threadIdx.x;
  const float4* p = (const float4*)(x + i*8);
  float4 a = p[0], b = p[1];
  u16x8 o;
  o[0]=f2b(a.x); o[1]=f2b(a.y); o[2]=f2b(a.z); o[3]=f2b(a.w);
  o[4]=f2b(b.x); o[5]=f2b(b.y); o[6]=f2b(b.z); o[7]=f2b(b.w);
  *(u16x8*)(y + i*8) = o;
}

// ------------------------------------------- W[K][N] f32 -> Wt[N][K] bf16 (x4 fused)
__global__ void transpose_w_kernel(const float* __restrict__ W0, const float* __restrict__ W1,
                                   const float* __restrict__ W2, const float* __restrict__ W3,
                                   unsigned short* __restrict__ T0, unsigned short* __restrict__ T1,
                                   unsigned short* __restrict__ T2, unsigned short* __restrict__ T3){
  __shared__ float tile[32][33];
  const int z = blockIdx.z;
  const float* W = z==0 ? W0 : z==1 ? W1 : z==2 ? W2 : W3;
  unsigned short* Wt = z==0 ? T0 : z==1 ? T1 : z==2 ? T2 : T3;
  int tx = threadIdx.x, ty = threadIdx.y;
  int x0 = blockIdx.x*32, y0 = blockIdx.y*32;
  #pragma unroll
  for (int i=0;i<4;i++)
    tile[ty + i*8][tx] = W[(size_t)(y0 + ty + i*8)*D_MODEL + x0 + tx];
  __syncthreads();
  #pragma unroll
  for (int i=0;i<4;i++)
    Wt[(size_t)(x0 + ty + i*8)*D_MODEL + y0 + tx] = f2b(tile[tx][ty + i*8]);
}

// ---------------------------------------------------------------- GEMM (B^T form)
// C[M][N] = A[M][K] * Bt[N][K]^T + bias, 128x128 tile, BK=32, DOUBLE-BUFFERED
// prefetch (T3-minimum: STAGE(next); compute(cur); barrier; swap).
// 64B LDS rows, 4 chunks; swizzle c_read = lg ^ ((r>>1)&3) (2-way banks = free).
// mode 0: bf16 row-major out. mode 1: V-transposed Vt[b][h][d][t] bf16.
__device__ __forceinline__ void gemm_body(const unsigned short* __restrict__ A,
                                          const unsigned short* __restrict__ Bt,
                                          const float* __restrict__ bias,
                                          void* __restrict__ Cout, const int mode,
                                          const int m0, const int n0)
{
  constexpr int K = D_MODEL, N = D_MODEL;
  __shared__ unsigned short As[2][128*32];   // 8KB per buf
  __shared__ unsigned short Bs[2][128*32];
  const int t = threadIdx.x, lane = t&63, w = t>>6;
  const int wr = w>>1, wc = w&1, lr = lane&15, lg = lane>>4;
  const int srow = lane>>2;                      // row within 16-row region
  const int schunk = (lane&3) ^ ((lane>>3)&3);   // involution source chunk
  const int crd = lg ^ ((lr>>1)&3);              // read chunk (lane-const)
  f32x4 acc[4][4] = {};

  auto stage = [&](int buf, int k0){
    #pragma unroll
    for (int g=0; g<2; g++){
      int reg = w*2 + g;                         // 8 regions of 16 rows
      int r = reg*16 + srow;
      gload16(A  + (size_t)(m0+r)*K + k0 + schunk*8, (char*)As[buf] + reg*1024);
      gload16(Bt + (size_t)(n0+r)*K + k0 + schunk*8, (char*)Bs[buf] + reg*1024);
    }
  };

  stage(0, 0);
  __syncthreads();
  int buf = 0;
  for (int ks = 0; ks < 32; ++ks){
    if (ks < 31) stage(buf^1, (ks+1)*32);
    const char* bufA = (const char*)As[buf];
    const char* bufB = (const char*)Bs[buf];
    bf16x8 af[4], bfv[4];
    #pragma unroll
    for (int mi=0;mi<4;mi++){
      int r = wr*64 + mi*16 + lr;
      af[mi] = *(const bf16x8*)(bufA + r*64 + crd*16);
    }
    #pragma unroll
    for (int ni=0;ni<4;ni++){
      int r = wc*64 + ni*16 + lr;
      bfv[ni] = *(const bf16x8*)(bufB + r*64 + crd*16);
    }
    #pragma unroll
    for (int mi=0;mi<4;mi++)
      #pragma unroll
      for (int ni=0;ni<4;ni++)
        acc[mi][ni] = mfma16(af[mi], bfv[ni], acc[mi][ni]);
    __syncthreads();
    buf ^= 1;
  }

  #pragma unroll
  for (int mi=0;mi<4;mi++){
    #pragma unroll
    for (int ni=0;ni<4;ni++){
      int n = n0 + wc*64 + ni*16 + lr;
      int mbase = m0 + wr*64 + mi*16 + lg*4;
      float bv = bias[n];
      if (mode == 0){
        unsigned short* Cb = (unsigned short*)Cout;
        #pragma unroll
        for (int r=0;r<4;r++) Cb[(size_t)(mbase+r)*N + n] = f2b(acc[mi][ni][r] + bv);
      } else {
        unsigned short* Vt = (unsigned short*)Cout;
        int h = n >> 6, d = n & 63;
        int b = mbase >> 11;
        int tq = mbase & (TT-1);
        u16x4 vv;
        #pragma unroll
        for (int r=0;r<4;r++) vv[r] = f2b(acc[mi][ni][r] + bv);
        *(u16x4*)(Vt + ((size_t)((b*NHEAD + h)*HDIM + d))*TT + tq) = vv;
      }
    }
  }
}

// proj: flat grid 768 = 8 xcd x 8 n x 4 m_inner x 3 z (T1 XCD-locality for A-panels)
__launch_bounds__(256)
__global__ void proj_gemm_kernel(const unsigned short* __restrict__ Xq,
                                 const unsigned short* __restrict__ Xk,
                                 const unsigned short* __restrict__ Xv,
                                 const unsigned short* __restrict__ Wtq,
                                 const unsigned short* __restrict__ Wtk,
                                 const unsigned short* __restrict__ Wtv,
                                 const float* __restrict__ b_q, const float* __restrict__ b_k,
                                 const float* __restrict__ b_v,
                                 unsigned short* __restrict__ Qb, unsigned short* __restrict__ Kb,
                                 unsigned short* __restrict__ Vt)
{
  const int id = blockIdx.x;
  const int xcd = id & 7, r2 = id >> 3;
  const int n = r2 & 7, mz = r2 >> 3;
  const int m = (mz & 3)*8 + xcd, z = mz >> 2;
  const unsigned short* A  = z==0 ? Xq : z==1 ? Xk : Xv;
  const unsigned short* Bt = z==0 ? Wtq : z==1 ? Wtk : Wtv;
  const float* bias = z==0 ? b_q : z==1 ? b_k : b_v;
  void* C = z==0 ? (void*)Qb : z==1 ? (void*)Kb : (void*)Vt;
  gemm_body(A, Bt, bias, C, z==2 ? 1 : 0, m*128, n*128);
}

// out-proj: 64x128 tiles, 512 blocks (2/CU), f32 output, same dbuf structure
__launch_bounds__(256)
__global__ void out_gemm_kernel(const unsigned short* __restrict__ Ob,
                                const unsigned short* __restrict__ Wto,
                                const float* __restrict__ b_o, float* __restrict__ out)
{
  constexpr int K = D_MODEL, N = D_MODEL;
  __shared__ unsigned short As[2][64*32];    // 4KB per buf
  __shared__ unsigned short Bs[2][128*32];   // 8KB per buf
  const int id = blockIdx.x;
  const int xcd = id & 7, r2 = id >> 3;
  const int n0 = (r2 & 7)*128, m0 = ((r2 >> 3)*8 + xcd)*64;
  const int t = threadIdx.x, lane = t&63, w = t>>6;
  const int wr = w>>1, wc = w&1, lr = lane&15, lg = lane>>4;
  const int srow = lane>>2;
  const int schunk = (lane&3) ^ ((lane>>3)&3);
  const int crd = lg ^ ((lr>>1)&3);
  f32x4 acc[2][4] = {};

  auto stage = [&](int buf, int k0){
    { int r = w*16 + srow;               // A: 4 regions, one per wave
      gload16(Ob + (size_t)(m0+r)*K + k0 + schunk*8, (char*)As[buf] + w*1024); }
    #pragma unroll
    for (int g=0; g<2; g++){
      int reg = w*2 + g;
      int r = reg*16 + srow;
      gload16(Wto + (size_t)(n0+r)*K + k0 + schunk*8, (char*)Bs[buf] + reg*1024);
    }
  };

  stage(0, 0);
  __syncthreads();
  int buf = 0;
  for (int ks = 0; ks < 32; ++ks){
    if (ks < 31) stage(buf^1, (ks+1)*32);
    const char* bufA = (const char*)As[buf];
    const char* bufB = (const char*)Bs[buf];
    bf16x8 af[2], bfv[4];
    #pragma unroll
    for (int mi=0;mi<2;mi++){
      int r = wr*32 + mi*16 + lr;
      af[mi] = *(const bf16x8*)(bufA + r*64 + crd*16);
    }
    #pragma unroll
    for (int ni=0;ni<4;ni++){
      int r = wc*64 + ni*16 + lr;
      bfv[ni] = *(const bf16x8*)(bufB + r*64 + crd*16);
    }
    #pragma unroll
    for (int mi=0;mi<2;mi++)
      #pragma unroll
      for (int ni=0;ni<4;ni++)
        acc[mi][ni] = mfma16(af[mi], bfv[ni], acc[mi][ni]);
    __syncthreads();
    buf ^= 1;
  }

  #pragma unroll
  for (int mi=0;mi<2;mi++){
    #pragma unroll
    for (int ni=0;ni<4;ni++){
      int n = n0 + wc*64 + ni*16 + lr;
      int mbase = m0 + wr*32 + mi*16 + lg*4;
      float bv = b_o[n];
      #pragma unroll
      for (int r=0;r<4;r++) out[(size_t)(mbase+r)*N + n] = acc[mi][ni][r] + bv;
    }
  }
}

// ------------------------------------------------------- Pass A: column sums
// partialS[qc][bh][col] = sum_{q in 256-chunk qc, q>=col} exp(S[q,col])
// 128B-row tiles, 8-chunk involution; Q double-buffered with prefetch.
__launch_bounds__(256)
__global__ void col_stats_kernel(const unsigned short* __restrict__ Qb,
                                 const unsigned short* __restrict__ Kb,
                                 float* __restrict__ partialS)
{
  __shared__ unsigned short Ks[128*64];      // 16KB static
  __shared__ unsigned short Qs[2][64*64];    // 8KB per buf
  const int t = threadIdx.x, lane = t&63, w = t>>6;
  const int id = blockIdx.x;
  const int bh = id & 31, pair = id >> 5;   // XCD = bh%8 -> per-bh L2 locality
  const int kb_ = pair & 15, qc = pair >> 4;
  const int b = bh >> 4, h = bh & 15;
  const int k0 = kb_ * 128;
  const int lr = lane&15, lg = lane>>4;
  const int osrc = (lane&7) ^ (lane>>3);

  auto stageQ = [&](int buf, int qt){
    #pragma unroll
    for (int g=0; g<2; g++){
      int reg = w*2 + g;
      int r = reg*8 + (lane>>3);
      gload16(Qb + ((size_t)(b*TT + qt + r))*D_MODEL + h*64 + osrc*8,
              (char*)Qs[buf] + reg*1024);
    }
  };

  const int qstart = (k0 > qc*256) ? k0 : qc*256;
  const int qend   = (qc+1)*256;

  #pragma unroll
  for (int g=0; g<4; g++){
    int reg = w*4 + g;
    int r = reg*8 + (lane>>3);
    gload16(Kb + ((size_t)(b*TT + k0 + r))*D_MODEL + h*64 + osrc*8, (char*)Ks + reg*1024);
  }
  if (qstart < qend) stageQ(0, qstart);
  __syncthreads();

  bf16x8 bk[2][2];
  #pragma unroll
  for (int kb=0;kb<2;kb++)
    #pragma unroll
    for (int ks=0;ks<2;ks++){
      int r = w*32 + kb*16 + lr;
      bk[kb][ks] = *(const bf16x8*)((const char*)Ks + r*128 + (((ks*4+lg) ^ (r&7))*16));
    }
  f32x4 sacc[2] = {};
  int buf = 0;
  for (int qt = qstart; qt < qend; qt += 64){
    if (qt + 64 < qend) stageQ(buf^1, qt+64);
    const char* bufQ = (const char*)Qs[buf];
    const bool interior = (qt >= k0 + 128);
    #pragma unroll
    for (int qb=0;qb<4;qb++){
      bf16x8 aq[2];
      #pragma unroll
      for (int ks=0;ks<2;ks++){
        int r = qb*16 + lr;
        aq[ks] = *(const bf16x8*)(bufQ + r*128 + (((ks*4+lg) ^ (r&7))*16));
      }
      f32x4 sf[2] = {};
      #pragma unroll
      for (int ks=0;ks<2;ks++)
        #pragma unroll
        for (int kb=0;kb<2;kb++)
          sf[kb] = mfma16(aq[ks], bk[kb][ks], sf[kb]);
      #pragma unroll
      for (int kb=0;kb<2;kb++){
        int col = k0 + w*32 + kb*16 + lr;
        #pragma unroll
        for (int r=0;r<4;r++){
          float e = __expf(sf[kb][r] * 0.125f);
          if (!interior){
            int qg = qt + qb*16 + lg*4 + r;
            e = (qg >= col) ? e : 0.f;
          }
          sacc[kb][r] += e;
        }
      }
    }
    __syncthreads();
    buf ^= 1;
  }
  #pragma unroll
  for (int kb=0;kb<2;kb++){
    float s = sacc[kb][0] + sacc[kb][1] + sacc[kb][2] + sacc[kb][3];
    s += __shfl_xor(s, 16);
    s += __shfl_xor(s, 32);
    if (lg == 0){
      int col = k0 + w*32 + kb*16 + lr;
      partialS[((size_t)qc*BHN + bh)*TT + col] = s;
    }
  }
}

__global__ void col_combine_kernel(const float* __restrict__ partialS, float* __restrict__ colS){
  int i = blockIdx.x*256 + threadIdx.x;
  float s = 0.f;
  #pragma unroll
  for (int qc=0;qc<8;qc++) s += partialS[(size_t)qc*BHN*TT + i];
  colS[i] = 1.0f / s;
}

// ---------------------------------------- V' = V * invs_k  (fold normalizer into V)
__global__ void vscale_kernel(unsigned short* __restrict__ Vt, const float* __restrict__ colS){
  size_t c = (size_t)blockIdx.x*256 + threadIdx.x;  // chunk of 8 t-values
  int t0  = (int)(c & 255) * 8;
  int row = (int)(c >> 8);            // bh*64 + d
  int bh  = row >> 6;
  u16x8 v = *(u16x8*)(Vt + (size_t)row*TT + t0);
  const float4* cs = (const float4*)(colS + (size_t)bh*TT + t0);
  float4 s0 = cs[0], s1 = cs[1];
  v[0]=f2b(b2f(v[0])*s0.x); v[1]=f2b(b2f(v[1])*s0.y);
  v[2]=f2b(b2f(v[2])*s0.z); v[3]=f2b(b2f(v[3])*s0.w);
  v[4]=f2b(b2f(v[4])*s1.x); v[5]=f2b(b2f(v[5])*s1.y);
  v[6]=f2b(b2f(v[6])*s1.z); v[7]=f2b(b2f(v[7])*s1.w);
  *(u16x8*)(Vt + (size_t)row*TT + t0) = v;
}

// ------------------------------------------------------------- Pass B: output
// O[q,:] = sum_{k<=q} exp(S[q,k]) * V'[k,:]  (V' pre-scaled by invs_k)
// Swapped QK^T; K/V double-buffered, prefetch hidden under S+P+PV compute.
__launch_bounds__(256)
__global__ void attn_out_kernel(const unsigned short* __restrict__ Qb,
                                const unsigned short* __restrict__ Kb,
                                const unsigned short* __restrict__ Vt,
                                unsigned short* __restrict__ O)
{
  __shared__ unsigned short Qs[64*64];       // 8KB
  __shared__ unsigned short Ks2[2][64*64];   // 8KB per buf
  __shared__ unsigned short Vs[2][64*64];
  __shared__ unsigned short Ps[64*64];       // 8KB (wave-private 16-row strips)
  const int t = threadIdx.x, lane=t&63, w=t>>6;
  const int id = blockIdx.x;
  const int bh = id & 31;                 // XCD = bh%8 -> K/V in one XCD's L2
  const int qi = 31 - (id >> 5);          // heavy blocks first
  const int b = bh>>4, h = bh&15;
  const int q0 = qi*64;
  const int lr = lane&15, lg = lane>>4;
  const int osrc = (lane&7) ^ (lane>>3);

  auto stageKV = [&](int buf, int k0){
    #pragma unroll
    for (int g=0; g<2; g++){
      int reg = w*2 + g;
      int r = reg*8 + (lane>>3);
      gload16(Kb + ((size_t)(b*TT + k0 + r))*D_MODEL + h*64 + osrc*8,
              (char*)Ks2[buf] + reg*1024);
      gload16(Vt + ((size_t)(bh*HDIM + r))*TT + k0 + osrc*8,
              (char*)Vs[buf] + reg*1024);
    }
  };

  #pragma unroll
  for (int g=0; g<2; g++){
    int reg = w*2 + g;
    int r = reg*8 + (lane>>3);
    gload16(Qb + ((size_t)(b*TT + q0 + r))*D_MODEL + h*64 + osrc*8, (char*)Qs + reg*1024);
  }
  stageKV(0, 0);
  __syncthreads();

  bf16x8 aq[2];
  #pragma unroll
  for (int ks=0;ks<2;ks++){
    int r = w*16 + lr;
    aq[ks] = *(const bf16x8*)((const char*)Qs + r*128 + (((ks*4+lg) ^ (r&7))*16));
  }
  f32x4 oacc[4] = {};
  const int nkt = qi + 1;
  int buf = 0;
  for (int kt=0; kt<nkt; kt++){
    int k0 = kt*64;
    if (kt+1 < nkt) stageKV(buf^1, k0+64);
    const char* bufK = (const char*)Ks2[buf];
    const char* bufV = (const char*)Vs[buf];
    // S^T = K . Q^T : col = q (lane&15), row = k (lg*4 + r within 16-block)
    f32x4 sf[4] = {};
    #pragma unroll
    for (int ks=0;ks<2;ks++)
      #pragma unroll
      for (int kb=0;kb<4;kb++){
        int r = kb*16 + lr;
        bf16x8 bk = *(const bf16x8*)(bufK + r*128 + (((ks*4+lg) ^ (r&7))*16));
        sf[kb] = mfma16(bk, aq[ks], sf[kb]);   // SWAPPED operands
      }
    // P = exp(S) (unnormalized); contiguous k-run of 4 -> one b64 LDS write
    const bool boundary = (kt == qi);
    const int prow = w*16 + lr;
    #pragma unroll
    for (int kb=0;kb<4;kb++){
      u16x4 vv;
      #pragma unroll
      for (int r=0;r<4;r++){
        float pv = __expf(sf[kb][r]*0.125f);
        if (boundary){
          int kg = k0 + kb*16 + lg*4 + r;
          int qg = q0 + prow;
          pv = (qg >= kg) ? pv : 0.f;
        }
        vv[r] = f2b(pv);
      }
      *(u16x4*)((char*)Ps + ((prow*128 + kb*32 + lg*8) ^ ((prow&7)<<4))) = vv;
    }
    // (Ps rows wave-private; in-wave lgkmcnt ordering suffices)
    #pragma unroll
    for (int ks=0;ks<2;ks++){
      bf16x8 pa = *(const bf16x8*)((const char*)Ps + prow*128 + (((ks*4+lg) ^ (prow&7))*16));
      #pragma unroll
      for (int db=0;db<4;db++){
        int r = db*16 + lr;
        bf16x8 bv = *(const bf16x8*)(bufV + r*128 + (((ks*4+lg) ^ (r&7))*16));
        oacc[db] = mfma16(pa, bv, oacc[db]);
      }
    }
    __syncthreads();
    buf ^= 1;
  }
  #pragma unroll
  for (int db=0;db<4;db++){
    int qg = q0 + w*16 + lg*4;
    int d  = db*16 + lr;
    #pragma unroll
    for (int r=0;r<4;r++)
      O[((size_t)(b*TT + qg + r))*D_MODEL + h*64 + d] = f2b(oacc[db][r]);
  }
}

// ---------------------------------------------------------------------- launch
extern "C" void kernel_launch(void* const* d_in, const int* in_sizes, int n_in,
                              void* d_out, int out_size, void* d_ws, size_t ws_size,
                              hipStream_t stream)
{
  (void)in_sizes; (void)n_in; (void)out_size; (void)ws_size;
  const float* q   = (const float*)d_in[0];
  const float* k   = (const float*)d_in[1];
  const float* v   = (const float*)d_in[2];
  const float* w_q = (const float*)d_in[3];
  const float* b_q = (const float*)d_in[4];
  const float* w_k = (const float*)d_in[5];
  const float* b_k = (const float*)d_in[6];
  const float* w_v = (const float*)d_in[7];
  const float* b_v = (const float*)d_in[8];
  const float* w_o = (const float*)d_in[9];
  const float* b_o = (const float*)d_in[10];

  char* p = (char*)d_ws;
  auto carve = [&](size_t bytes)->char* {
    char* r = p; p += (bytes + 255) & ~(size_t)255; return r;
  };
  unsigned short* Xq  = (unsigned short*)carve((size_t)MM*D_MODEL*2);
  unsigned short* Xk  = (unsigned short*)carve((size_t)MM*D_MODEL*2);
  unsigned short* Xv  = (unsigned short*)carve((size_t)MM*D_MODEL*2);
  unsigned short* Wtq = (unsigned short*)carve((size_t)D_MODEL*D_MODEL*2);
  unsigned short* Wtk = (unsigned short*)carve((size_t)D_MODEL*D_MODEL*2);
  unsigned short* Wtv = (unsigned short*)carve((size_t)D_MODEL*D_MODEL*2);
  unsigned short* Wto = (unsigned short*)carve((size_t)D_MODEL*D_MODEL*2);
  unsigned short* Qb  = (unsigned short*)carve((size_t)MM*D_MODEL*2);
  unsigned short* Kb  = (unsigned short*)carve((size_t)MM*D_MODEL*2);
  unsigned short* Vt  = (unsigned short*)carve((size_t)MM*D_MODEL*2);
  unsigned short* Ob  = (unsigned short*)carve((size_t)MM*D_MODEL*2);
  float* partialS = (float*)carve((size_t)8*BHN*TT*4);
  float* colS     = (float*)carve((size_t)BHN*TT*4);

  cvt_bf16_kernel<<<dim3((MM*D_MODEL/8)/256, 3), 256, 0, stream>>>(q, k, v, Xq, Xk, Xv);

  dim3 tgrid(32,32,4), tblk(32,8);
  transpose_w_kernel<<<tgrid, tblk, 0, stream>>>(w_q, w_k, w_v, w_o, Wtq, Wtk, Wtv, Wto);

  proj_gemm_kernel<<<dim3(768), 256, 0, stream>>>(Xq, Xk, Xv, Wtq, Wtk, Wtv,
                                                  b_q, b_k, b_v, Qb, Kb, Vt);

  col_stats_kernel<<<dim3(8*16*BHN), 256, 0, stream>>>(Qb, Kb, partialS);
  col_combine_kernel<<<dim3(BHN*TT/256), 256, 0, stream>>>(partialS, colS);

  vscale_kernel<<<dim3((BHN*HDIM*TT/8)/256), 256, 0, stream>>>(Vt, colS);

  attn_out_kernel<<<dim3((TT/64)*BHN), 256, 0, stream>>>(Qb, Kb, Vt, Ob);

  out_gemm_kernel<<<dim3(512), 256, 0, stream>>>(Ob, Wto, b_o, (float*)d_out);
}